// Round 8
// baseline (475.094 us; speedup 1.0000x reference)
//
#include <hip/hip_runtime.h>

// GraphSAGE (mean) x3 + per-graph mean pool, MI355X.
// R8: CSR build rewritten as a two-level counting sort. R7 falsified the
// "read-stream eviction" theory (nt loads changed nothing); real problem is
// the temporally-scattered 4B write frontier (each adj line dirtied ~10x).
// New build: bucket histogram (N/64 buckets) -> scan -> packed scatter with a
// ~100KB write frontier -> per-bucket LDS counting sort with COALESCED adj
// and offs writes. Replaces count_deg + 3 scans + fill_adj.
// NOTE: packs (d&63)<<26|src into 32 bits: requires N < 2^26 (here N=100k).

#define DD 64
#define CAP 4096   // per-bucket LDS sort capacity (avg bucket = 640 edges)

typedef __attribute__((ext_vector_type(8))) short short8;   // 8 bf16 (4 VGPRs)
typedef __attribute__((ext_vector_type(4))) float f32x4;    // MFMA accumulator

__device__ inline short8 pack4(unsigned a, unsigned b, unsigned c, unsigned d) {
    union { uint4 u; short8 s; } un;
    un.u = make_uint4(a, b, c, d);
    return un.s;
}

__device__ inline unsigned rne_bf16(float v) {   // round-to-nearest-even, high16
    unsigned u = __float_as_uint(v);
    return (u + 0x7FFFu + ((u >> 16) & 1u)) >> 16;
}

// ---------------- CSR build: two-level counting sort ----------------
__global__ __launch_bounds__(256) void bucket_count(
    const int* __restrict__ dst, int* __restrict__ bcnt, int E) {
    const int stride = gridDim.x * 256;
    for (int e = blockIdx.x * 256 + threadIdx.x; e < E; e += stride)
        atomicAdd(&bcnt[__builtin_nontemporal_load(dst + e) >> 6], 1);
}

// single-block scan over NB buckets -> boff/bcur; also offs[N]=E, boff[NB]=E
__global__ __launch_bounds__(1024) void bscan(
    const int* __restrict__ bcnt, int* __restrict__ boff, int* __restrict__ bcur,
    int* __restrict__ offs, int NB, int E, int N) {
    __shared__ int s[1024];
    __shared__ int carry_s;
    const int t = threadIdx.x;
    if (t == 0) carry_s = 0;
    __syncthreads();
    for (int cs = 0; cs < NB; cs += 1024) {
        const int i = cs + t;
        s[t] = (i < NB) ? bcnt[i] : 0;
        __syncthreads();
        for (int o = 1; o < 1024; o <<= 1) {
            int a = (t >= o) ? s[t - o] : 0;
            __syncthreads();
            s[t] += a;
            __syncthreads();
        }
        const int carry = carry_s;
        if (i < NB) {
            const int excl = carry + (t > 0 ? s[t - 1] : 0);
            boff[i] = excl;
            bcur[i] = excl;
        }
        __syncthreads();
        if (t == 1023) carry_s = carry + s[1023];
        __syncthreads();
    }
    if (t == 0) { boff[NB] = E; offs[N] = E; }
}

// scatter packed (local_d, src) words into bucket-ordered ebuf.
// Write frontier = NB line-tails (~100KB) -> lines fill fast, write back once.
__global__ __launch_bounds__(256) void bucket_scatter(
    const int* __restrict__ src, const int* __restrict__ dst,
    int* __restrict__ bcur, unsigned* __restrict__ ebuf, int E) {
    const int stride = gridDim.x * 256;
    for (int e = blockIdx.x * 256 + threadIdx.x; e < E; e += stride) {
        const int d = __builtin_nontemporal_load(dst + e);
        const int s = __builtin_nontemporal_load(src + e);
        const int pos = atomicAdd(&bcur[d >> 6], 1);
        ebuf[pos] = ((unsigned)(d & 63) << 26) | (unsigned)s;
    }
}

// one block per bucket: LDS counting sort over 64 nodes; coalesced adj/offs.
__global__ __launch_bounds__(256) void bucket_sort(
    const unsigned* __restrict__ ebuf, const int* __restrict__ boff,
    int* __restrict__ offs, int* __restrict__ adj, int N) {
    const int b  = blockIdx.x;
    const int lo = boff[b];
    const int sz = boff[b + 1] - lo;
    const int base = b << 6;
    const int t = threadIdx.x;

    __shared__ int hist[64];
    __shared__ int hcur[64];
    __shared__ unsigned sbuf[CAP];

    if (t < 64) hist[t] = 0;
    __syncthreads();
    for (int i = t; i < sz; i += 256)
        atomicAdd(&hist[ebuf[lo + i] >> 26], 1);
    __syncthreads();
    if (t == 0) {                       // tiny exclusive scan (64 entries)
        int run = 0;
        for (int k = 0; k < 64; ++k) { hcur[k] = run; run += hist[k]; }
    }
    __syncthreads();
    if (t < 64 && base + t < N) offs[base + t] = lo + hcur[t];
    __syncthreads();                    // offs must read hcur before scatter mutates

    if (sz <= CAP) {
        for (int i = t; i < sz; i += 256) {
            const unsigned w = ebuf[lo + i];
            const int p = atomicAdd(&hcur[w >> 26], 1);
            sbuf[p] = w & 0x03FFFFFFu;
        }
        __syncthreads();
        for (int i = t; i < sz; i += 256) adj[lo + i] = (int)sbuf[i];   // coalesced
    } else {                            // rare skewed bucket: direct scatter
        for (int i = t; i < sz; i += 256) {
            const unsigned w = ebuf[lo + i];
            const int p = atomicAdd(&hcur[w >> 26], 1);
            adj[lo + p] = (int)(w & 0x03FFFFFFu);
        }
    }
}

// ---------------- fp32 -> bf16 (RNE) cast, 8 elems/thread ----------------
__global__ __launch_bounds__(256) void cast_bf16(
    const float* __restrict__ in, unsigned short* __restrict__ outb, long long n8) {
    const long long t = (long long)blockIdx.x * 256 + threadIdx.x;
    if (t >= n8) return;
    const float4 v0 = *reinterpret_cast<const float4*>(in + t * 8);
    const float4 v1 = *reinterpret_cast<const float4*>(in + t * 8 + 4);
    uint4 o;
    o.x = rne_bf16(v0.x) | (rne_bf16(v0.y) << 16);
    o.y = rne_bf16(v0.z) | (rne_bf16(v0.w) << 16);
    o.z = rne_bf16(v1.x) | (rne_bf16(v1.y) << 16);
    o.w = rne_bf16(v1.z) | (rne_bf16(v1.w) << 16);
    *reinterpret_cast<uint4*>(outb + t * 8) = o;
}

// ---------------- gather-mean from bf16 rows (8 threads/node) --------------
__global__ __launch_bounds__(256) void aggregate_bf16(
    const unsigned short* __restrict__ xb, float* __restrict__ agg,
    const int* __restrict__ offs, const int* __restrict__ adj, int n) {
    const int t  = blockIdx.x * 256 + threadIdx.x;
    const int nd = t >> 3;
    const int c8 = (t & 7) * 8;
    if (nd >= n) return;

    const int s = offs[nd];
    const int e = offs[nd + 1];

    float a0[8], a1[8], a2[8], a3[8];
#pragma unroll
    for (int p = 0; p < 8; ++p) { a0[p] = 0.f; a1[p] = 0.f; a2[p] = 0.f; a3[p] = 0.f; }

#define ACC8(A, U)                                                             \
    do {                                                                       \
        A[0] += __uint_as_float((U).x << 16);                                  \
        A[1] += __uint_as_float((U).x & 0xFFFF0000u);                          \
        A[2] += __uint_as_float((U).y << 16);                                  \
        A[3] += __uint_as_float((U).y & 0xFFFF0000u);                          \
        A[4] += __uint_as_float((U).z << 16);                                  \
        A[5] += __uint_as_float((U).z & 0xFFFF0000u);                          \
        A[6] += __uint_as_float((U).w << 16);                                  \
        A[7] += __uint_as_float((U).w & 0xFFFF0000u);                          \
    } while (0)

    int j = s;
    for (; j + 4 <= e; j += 4) {
        const int i0 = adj[j], i1 = adj[j + 1], i2 = adj[j + 2], i3 = adj[j + 3];
        const uint4 u0 = *reinterpret_cast<const uint4*>(xb + (size_t)i0 * DD + c8);
        const uint4 u1 = *reinterpret_cast<const uint4*>(xb + (size_t)i1 * DD + c8);
        const uint4 u2 = *reinterpret_cast<const uint4*>(xb + (size_t)i2 * DD + c8);
        const uint4 u3 = *reinterpret_cast<const uint4*>(xb + (size_t)i3 * DD + c8);
        ACC8(a0, u0); ACC8(a1, u1); ACC8(a2, u2); ACC8(a3, u3);
    }
    for (; j < e; ++j) {
        const uint4 u = *reinterpret_cast<const uint4*>(xb + (size_t)adj[j] * DD + c8);
        ACC8(a0, u);
    }
#undef ACC8

    const int deg = e - s;
    const float inv = (deg > 0) ? (1.0f / (float)deg) : 1.0f;
    float4 r0, r1;
    r0.x = (a0[0] + a1[0] + a2[0] + a3[0]) * inv;
    r0.y = (a0[1] + a1[1] + a2[1] + a3[1]) * inv;
    r0.z = (a0[2] + a1[2] + a2[2] + a3[2]) * inv;
    r0.w = (a0[3] + a1[3] + a2[3] + a3[3]) * inv;
    r1.x = (a0[4] + a1[4] + a2[4] + a3[4]) * inv;
    r1.y = (a0[5] + a1[5] + a2[5] + a3[5]) * inv;
    r1.z = (a0[6] + a1[6] + a2[6] + a3[6]) * inv;
    r1.w = (a0[7] + a1[7] + a2[7] + a3[7]) * inv;
    *reinterpret_cast<float4*>(agg + (size_t)nd * DD + c8)     = r0;
    *reinterpret_cast<float4*>(agg + (size_t)nd * DD + c8 + 4) = r1;
}

// ---------------- fp32 gather fallback (16 threads/node) ----------------
__global__ __launch_bounds__(256) void aggregate(
    const float* __restrict__ xin, float* __restrict__ agg,
    const int* __restrict__ offs, const int* __restrict__ adj, int n) {
    const int t  = blockIdx.x * 256 + threadIdx.x;
    const int nd = t >> 4;
    const int c  = (t & 15) * 4;
    if (nd >= n) return;
    const int s = offs[nd];
    const int e = offs[nd + 1];
    float4 a0 = {0.f, 0.f, 0.f, 0.f};
    float4 a1 = {0.f, 0.f, 0.f, 0.f};
    float4 a2 = {0.f, 0.f, 0.f, 0.f};
    float4 a3 = {0.f, 0.f, 0.f, 0.f};
    int j = s;
    for (; j + 4 <= e; j += 4) {
        const int i0 = adj[j], i1 = adj[j + 1], i2 = adj[j + 2], i3 = adj[j + 3];
        const float4 v0 = *reinterpret_cast<const float4*>(xin + (size_t)i0 * DD + c);
        const float4 v1 = *reinterpret_cast<const float4*>(xin + (size_t)i1 * DD + c);
        const float4 v2 = *reinterpret_cast<const float4*>(xin + (size_t)i2 * DD + c);
        const float4 v3 = *reinterpret_cast<const float4*>(xin + (size_t)i3 * DD + c);
        a0.x += v0.x; a0.y += v0.y; a0.z += v0.z; a0.w += v0.w;
        a1.x += v1.x; a1.y += v1.y; a1.z += v1.z; a1.w += v1.w;
        a2.x += v2.x; a2.y += v2.y; a2.z += v2.z; a2.w += v2.w;
        a3.x += v3.x; a3.y += v3.y; a3.z += v3.z; a3.w += v3.w;
    }
    for (; j < e; ++j) {
        const float4 v = *reinterpret_cast<const float4*>(xin + (size_t)adj[j] * DD + c);
        a0.x += v.x; a0.y += v.y; a0.z += v.z; a0.w += v.w;
    }
    const int deg = e - s;
    const float inv = (deg > 0) ? (1.0f / (float)deg) : 1.0f;
    float4 r;
    r.x = (a0.x + a1.x + a2.x + a3.x) * inv;
    r.y = (a0.y + a1.y + a2.y + a3.y) * inv;
    r.z = (a0.z + a1.z + a2.z + a3.z) * inv;
    r.w = (a0.w + a1.w + a2.w + a3.w) * inv;
    *reinterpret_cast<float4*>(agg + (size_t)nd * DD + c) = r;
}

// ---------------- W pre-pack into MFMA B-fragment layout, bf16 hi/lo --------
__global__ void pack_B(const float* __restrict__ Wl, const float* __restrict__ Wr,
                       unsigned* __restrict__ Bp, int L) {
    int t = blockIdx.x * 256 + threadIdx.x;
    int wv = t >> 6, lane = t & 63;
    if (wv >= L * 16) return;
    int layer = wv >> 4;
    int fid = wv & 15;
    int ks = fid >> 2, nt = fid & 3;
    int j = nt * 16 + (lane & 15);
    int kb = ks * 32 + (lane >> 4) * 8;
    const float* wl = Wl + (size_t)layer * DD * DD;
    const float* wr = Wr + (size_t)layer * DD * DD;
    unsigned hi[8], lo[8];
#pragma unroll
    for (int s = 0; s < 8; ++s) {
        int k = kb + s;
        float v = (k < DD) ? wl[k * DD + j] : wr[(k - DD) * DD + j];
        unsigned u = __float_as_uint(v);
        unsigned h = u & 0xFFFF0000u;
        hi[s] = h;
        float lf = v - __uint_as_float(h);         // exact residual
        lo[s] = __float_as_uint(lf) & 0xFFFF0000u;
    }
    size_t base_hi = ((size_t)(layer * 2 + 0) * 16 + fid) * 64 + lane;
    size_t base_lo = ((size_t)(layer * 2 + 1) * 16 + fid) * 64 + lane;
#pragma unroll
    for (int p = 0; p < 4; ++p) {
        Bp[base_hi * 4 + p] = (hi[2 * p] >> 16) | hi[2 * p + 1];
        Bp[base_lo * 4 + p] = (lo[2 * p] >> 16) | lo[2 * p + 1];
    }
}

// ---------------- layer GEMM + optional bf16 copy of the output -------------
__global__ __launch_bounds__(256, 2) void mfma_gemm(
    const float* __restrict__ g, const float* __restrict__ x,
    float* __restrict__ out, unsigned short* __restrict__ outb,   // may be null
    const unsigned* __restrict__ Bp, const float* __restrict__ bias, int n) {
    const int lane = threadIdx.x & 63;
    const int wv   = (int)((blockIdx.x * 256 + threadIdx.x) >> 6);
    const int nwv  = (int)((gridDim.x * 256) >> 6);

    short8 Bh[4][4], Bl[4][4];
#pragma unroll
    for (int ks = 0; ks < 4; ++ks)
#pragma unroll
        for (int nt = 0; nt < 4; ++nt) {
            int fid = ks * 4 + nt;
            const uint4 h = *reinterpret_cast<const uint4*>(Bp + ((size_t)fid * 64 + lane) * 4);
            const uint4 l = *reinterpret_cast<const uint4*>(Bp + ((size_t)(16 + fid) * 64 + lane) * 4);
            Bh[ks][nt] = pack4(h.x, h.y, h.z, h.w);
            Bl[ks][nt] = pack4(l.x, l.y, l.z, l.w);
        }

    float bv[4];
#pragma unroll
    for (int nt = 0; nt < 4; ++nt) bv[nt] = bias[nt * 16 + (lane & 15)];

    const int ntiles = (n + 15) >> 4;
    for (int tile = wv; tile < ntiles; tile += nwv) {
        const int row = tile * 16 + (lane & 15);
        const bool ok = row < n;
        const float* grow = g + (size_t)row * DD + (lane >> 4) * 8;
        const float* xrow = x + (size_t)row * DD + (lane >> 4) * 8;

        f32x4 acc[4];
#pragma unroll
        for (int nt = 0; nt < 4; ++nt) acc[nt] = (f32x4){bv[nt], bv[nt], bv[nt], bv[nt]};

#pragma unroll
        for (int ks = 0; ks < 4; ++ks) {
            const float* base = ((ks < 2) ? grow : xrow) + (ks & 1) * 32;
            f32x4 v0 = ok ? *reinterpret_cast<const f32x4*>(base)
                          : (f32x4){0.f, 0.f, 0.f, 0.f};
            f32x4 v1 = ok ? *reinterpret_cast<const f32x4*>(base + 4)
                          : (f32x4){0.f, 0.f, 0.f, 0.f};
            float vv[8] = {v0[0], v0[1], v0[2], v0[3], v1[0], v1[1], v1[2], v1[3]};
            unsigned hu[4], lu[4];
#pragma unroll
            for (int p = 0; p < 4; ++p) {
                unsigned ua = __float_as_uint(vv[2 * p]);
                unsigned ub = __float_as_uint(vv[2 * p + 1]);
                unsigned ha = ua & 0xFFFF0000u, hb = ub & 0xFFFF0000u;
                hu[p] = (ha >> 16) | hb;
                float la = vv[2 * p]     - __uint_as_float(ha);
                float lb = vv[2 * p + 1] - __uint_as_float(hb);
                lu[p] = ((__float_as_uint(la) & 0xFFFF0000u) >> 16) |
                        (__float_as_uint(lb) & 0xFFFF0000u);
            }
            const short8 Ah = pack4(hu[0], hu[1], hu[2], hu[3]);
            const short8 Al = pack4(lu[0], lu[1], lu[2], lu[3]);
#pragma unroll
            for (int nt = 0; nt < 4; ++nt) {
                acc[nt] = __builtin_amdgcn_mfma_f32_16x16x32_bf16(Ah, Bh[ks][nt], acc[nt], 0, 0, 0);
                acc[nt] = __builtin_amdgcn_mfma_f32_16x16x32_bf16(Al, Bh[ks][nt], acc[nt], 0, 0, 0);
                acc[nt] = __builtin_amdgcn_mfma_f32_16x16x32_bf16(Ah, Bl[ks][nt], acc[nt], 0, 0, 0);
            }
        }

        // C/D layout (verified): col = lane&15, row = (lane>>4)*4 + reg
        const int r0 = tile * 16 + (lane >> 4) * 4;
#pragma unroll
        for (int r = 0; r < 4; ++r) {
            const int rr = r0 + r;
            if (rr < n) {
#pragma unroll
                for (int nt = 0; nt < 4; ++nt) {
                    const float v = acc[nt][r];
                    const size_t idx = (size_t)rr * DD + nt * 16 + (lane & 15);
                    out[idx] = v;
                    if (outb) outb[idx] = (unsigned short)rne_bf16(v);
                }
            }
        }
    }
}

// ---------------- pooling partials over TWO arrays at once ----------------
__global__ __launch_bounds__(256) void pool_partial2(
    const float* __restrict__ xa, const float* __restrict__ xb,
    const int* __restrict__ batch,
    float* __restrict__ sumsA, float* __restrict__ sumsB, int n) {
    const int lane = threadIdx.x & 63;
    const int wv   = (int)((blockIdx.x * blockDim.x + threadIdx.x) >> 6);
    const int nwv  = (int)((gridDim.x * blockDim.x) >> 6);
    const int chunk = (n + nwv - 1) / nwv;
    const int start = wv * chunk;
    if (start >= n) return;
    const int end = min(start + chunk, n);

    int g = batch[start];
    float accA = 0.f, accB = 0.f;
    for (int nd = start; nd < end; ++nd) {
        const int bg = batch[nd];
        if (bg != g) {
            atomicAdd(&sumsA[(size_t)g * DD + lane], accA);
            atomicAdd(&sumsB[(size_t)g * DD + lane], accB);
            accA = 0.f; accB = 0.f;
            g = bg;
        }
        accA += xa[(size_t)nd * DD + lane];
        accB += xb[(size_t)nd * DD + lane];
    }
    atomicAdd(&sumsA[(size_t)g * DD + lane], accA);
    atomicAdd(&sumsB[(size_t)g * DD + lane], accB);
}

// ---------------- final: out[g] = mean(agg3)@Wl + mean(x2)@Wr + b ----------
__global__ void final_gemm(const float* __restrict__ sumsA, const float* __restrict__ sumsX,
                           const int* __restrict__ batch,
                           const float* __restrict__ Wl, const float* __restrict__ bl,
                           const float* __restrict__ Wr,
                           float* __restrict__ out, int n) {
    const int g = blockIdx.x;
    const int d = threadIdx.x;  // 64 threads

    int lo = 0, hi = n;
    while (lo < hi) { int m = (lo + hi) >> 1; if (batch[m] < g) lo = m + 1; else hi = m; }
    const int st = lo;
    lo = 0; hi = n;
    while (lo < hi) { int m = (lo + hi) >> 1; if (batch[m] < g + 1) lo = m + 1; else hi = m; }
    const int c = lo - st;

    if (c == 0) {                    // reference: empty graph -> 0 (not bias)
        out[(size_t)g * DD + d] = 0.f;
        return;
    }
    const float inv = 1.0f / (float)c;

    __shared__ float sa[DD], sx[DD];
    sa[d] = sumsA[(size_t)g * DD + d] * inv;
    sx[d] = sumsX[(size_t)g * DD + d] * inv;
    __syncthreads();

    float acc = bl[d];
#pragma unroll 8
    for (int k = 0; k < DD; ++k) acc += sa[k] * Wl[k * DD + d];
#pragma unroll 8
    for (int k = 0; k < DD; ++k) acc += sx[k] * Wr[k * DD + d];
    out[(size_t)g * DD + d] = acc;
}

extern "C" void kernel_launch(void* const* d_in, const int* in_sizes, int n_in,
                              void* d_out, int out_size, void* d_ws, size_t ws_size,
                              hipStream_t stream) {
    const float* x     = (const float*)d_in[0];
    const int*   ei    = (const int*)d_in[1];
    const int*   batch = (const int*)d_in[2];
    const float* Wl    = (const float*)d_in[3];
    const float* bl    = (const float*)d_in[4];
    const float* Wr    = (const float*)d_in[5];

    const int N = in_sizes[0] / DD;
    const int E = in_sizes[1] / 2;
    const int L = in_sizes[3] / (DD * DD);
    const int G = out_size / DD;
    const int NB = (N + 63) >> 6;

    const int* src = ei;        // edge_index[0]
    const int* dst = ei + E;    // edge_index[1]

    char* ws = (char*)d_ws;
    size_t off = 0;
    auto alloc = [&](size_t bytes) -> char* {
        char* p = ws + off;
        off += (bytes + 255) & ~(size_t)255;
        return p;
    };
    int*      offs   = (int*)alloc((size_t)(N + 1) * 4);
    int*      adj    = (int*)alloc((size_t)E * 4);
    int*      bcnt   = (int*)alloc((size_t)(NB + 1) * 4);
    int*      boff   = (int*)alloc((size_t)(NB + 1) * 4);
    int*      bcur   = (int*)alloc((size_t)(NB + 1) * 4);
    unsigned* ebuf   = (unsigned*)alloc((size_t)E * 4);
    float*    b0     = (float*)alloc((size_t)N * DD * 4);
    float*    b1     = (float*)alloc((size_t)N * DD * 4);
    float*    aggbuf = (float*)alloc((size_t)N * DD * 4);
    unsigned* Bp     = (unsigned*)alloc((size_t)L * 2 * 16 * 64 * 4 * 4);
    float*    sumsA  = (float*)alloc((size_t)G * DD * 4);
    float*    sumsX  = (float*)alloc((size_t)G * DD * 4);
    const size_t bfbytes = (size_t)N * DD * 2;
    unsigned short* bfA = (unsigned short*)alloc(bfbytes);
    unsigned short* bfB = (unsigned short*)alloc(bfbytes);
    const bool use_bf16 = (off <= ws_size);

    // ---- CSR build: bucket count -> scan -> scatter -> per-bucket sort ----
    hipMemsetAsync(bcnt, 0, (size_t)(NB + 1) * 4, stream);
    bucket_count<<<2048, 256, 0, stream>>>(dst, bcnt, E);
    bscan<<<1, 1024, 0, stream>>>(bcnt, boff, bcur, offs, NB, E, N);
    bucket_scatter<<<2048, 256, 0, stream>>>(src, dst, bcur, ebuf, E);
    bucket_sort<<<NB, 256, 0, stream>>>(ebuf, boff, offs, adj, N);

    // ---- pack W into MFMA fragment layout (all layers) ----
    pack_B<<<(L * 16 * 64 + 255) / 256, 256, 0, stream>>>(Wl, Wr, Bp, L);

    // ---- layers 0..L-2: aggregate + MFMA gemm (ping-pong) ----
    const float* cur = x;
    float* bufs[2] = {b0, b1};
    unsigned short* bfs[2] = {bfB, bfA};   // gemm layer l writes bfs[l&1]
    const unsigned short* curb = bfA;      // bf16 view of cur

    if (use_bf16) {
        const long long n8 = (long long)N * DD / 8;
        cast_bf16<<<(int)((n8 + 255) / 256), 256, 0, stream>>>(x, bfA, n8);
    }

    const int aggB_blocks = (N * 8 + 255) / 256;
    const int aggF_blocks = (N * 16 + 255) / 256;
    for (int l = 0; l < L - 1; ++l) {
        float* outb = bufs[l & 1];
        if (use_bf16) {
            aggregate_bf16<<<aggB_blocks, 256, 0, stream>>>(curb, aggbuf, offs, adj, N);
        } else {
            aggregate<<<aggF_blocks, 256, 0, stream>>>(cur, aggbuf, offs, adj, N);
        }
        mfma_gemm<<<1024, 256, 0, stream>>>(aggbuf, cur, outb,
                                            use_bf16 ? bfs[l & 1] : (unsigned short*)nullptr,
                                            Bp + (size_t)l * 2 * 16 * 64 * 4,
                                            bl + (size_t)l * DD, N);
        cur = outb;
        curb = bfs[l & 1];
    }

    // ---- last layer: pooling is linear -> pool(agg), pool(x), tiny GEMM ----
    if (use_bf16) {
        aggregate_bf16<<<aggB_blocks, 256, 0, stream>>>(curb, aggbuf, offs, adj, N);
    } else {
        aggregate<<<aggF_blocks, 256, 0, stream>>>(cur, aggbuf, offs, adj, N);
    }
    hipMemsetAsync(sumsA, 0, (size_t)G * DD * 4, stream);
    hipMemsetAsync(sumsX, 0, (size_t)G * DD * 4, stream);
    pool_partial2<<<2048, 256, 0, stream>>>(aggbuf, cur, batch, sumsA, sumsX, N);
    final_gemm<<<G, DD, 0, stream>>>(sumsA, sumsX, batch,
                                     Wl + (size_t)(L - 1) * DD * DD,
                                     bl + (size_t)(L - 1) * DD,
                                     Wr + (size_t)(L - 1) * DD * DD,
                                     (float*)d_out, N);
}

// Round 9
// 275.704 us; speedup vs baseline: 1.7232x; 1.7232x over previous
//
#include <hip/hip_runtime.h>

// GraphSAGE (mean) x3 + per-graph mean pool, MI355X.
// R9: CSR front-end rebuilt as atomic-free private-region partition.
// R8 lesson: narrow-but-SHARED write frontier + 640-deep same-address atomics
// serialize cross-XCD (152us). Fix: (1) per-(block,seg) exact ranges computed
// from counts -> scatter has NO global atomics, each block writes a private
// ~31KB region (one writeback); (2) seg_fill is XCD-affine and streams only
// its segment's 1MB (vs 8MB through a 4MB L2 -- the R4/R6 eviction bug).
// deg histogram merged into seg_count (removes the 8x-reread count_deg).

#define DD 64
#define NSEG 8
#define ABLK 256   // pass-A blocks

typedef __attribute__((ext_vector_type(8))) short short8;   // 8 bf16 (4 VGPRs)
typedef __attribute__((ext_vector_type(4))) float f32x4;    // MFMA accumulator

__device__ inline short8 pack4(unsigned a, unsigned b, unsigned c, unsigned d) {
    union { uint4 u; short8 s; } un;
    un.u = make_uint4(a, b, c, d);
    return un.s;
}

__device__ inline unsigned rne_bf16(float v) {   // round-to-nearest-even, high16
    unsigned u = __float_as_uint(v);
    return (u + 0x7FFFu + ((u >> 16) & 1u)) >> 16;
}

// ---------------- CSR pass A1: per-block seg counts + global deg ------------
__global__ __launch_bounds__(256) void seg_count(
    const int* __restrict__ dst, int* __restrict__ deg,
    int* __restrict__ cnt /*[ABLK][NSEG]*/, int E, int segsz) {
    __shared__ int lc[NSEG];
    const int b = blockIdx.x;
    const int per = (E + ABLK - 1) / ABLK;
    const int lo = b * per, hi = min(lo + per, E);
    if (threadIdx.x < NSEG) lc[threadIdx.x] = 0;
    __syncthreads();
    for (int e = lo + threadIdx.x; e < hi; e += 256) {
        const int d = dst[e];
        atomicAdd(&deg[d], 1);
        atomicAdd(&lc[d / segsz], 1);
    }
    __syncthreads();
    if (threadIdx.x < NSEG) cnt[b * NSEG + threadIdx.x] = lc[threadIdx.x];
}

// ---------------- CSR pass A2: exact private ranges -------------------------
// base[b][s] = segoff[s] + sum_{b'<b} cnt[b'][s]
__global__ __launch_bounds__(256) void seg_base(
    const int* __restrict__ cnt, int* __restrict__ base,
    int* __restrict__ segoff, int E) {
    __shared__ int tot[NSEG];
    __shared__ int soff[NSEG + 1];
    const int t = threadIdx.x;
    if (t < NSEG) {
        int run = 0;
        for (int b = 0; b < ABLK; ++b) {
            base[b * NSEG + t] = run;
            run += cnt[b * NSEG + t];
        }
        tot[t] = run;
    }
    __syncthreads();
    if (t == 0) {
        int run = 0;
        for (int s = 0; s < NSEG; ++s) { soff[s] = run; run += tot[s]; }
        soff[NSEG] = run;   // == E
        for (int s = 0; s <= NSEG; ++s) segoff[s] = soff[s];
    }
    __syncthreads();
    for (int i = t; i < ABLK * NSEG; i += 256) base[i] += soff[i & 7];
}

// ---------------- CSR pass A3: atomic-free private-region scatter -----------
__global__ __launch_bounds__(256) void seg_scatter(
    const int* __restrict__ src, const int* __restrict__ dst,
    const int* __restrict__ base, int* __restrict__ sdst,
    int* __restrict__ ssrc, int E, int segsz) {
    __shared__ int pos[NSEG];
    const int b = blockIdx.x;
    const int per = (E + ABLK - 1) / ABLK;
    const int lo = b * per, hi = min(lo + per, E);
    if (threadIdx.x < NSEG) pos[threadIdx.x] = base[b * NSEG + threadIdx.x];
    __syncthreads();
    for (int e = lo + threadIdx.x; e < hi; e += 256) {
        const int d = dst[e];
        const int s = src[e];
        const int p = atomicAdd(&pos[d / segsz], 1);   // LDS only
        sdst[p] = d;
        ssrc[p] = s;
    }
}

// ---------------- scans (deg -> offs, cursor fused) ----------------
__global__ void scan1(const int* __restrict__ deg, int* __restrict__ offs,
                      int* __restrict__ bsum, int n) {
    __shared__ int s[1024];
    int t = threadIdx.x;
    int i = blockIdx.x * 1024 + t;
    int v = (i < n) ? deg[i] : 0;
    s[t] = v;
    __syncthreads();
    for (int o = 1; o < 1024; o <<= 1) {
        int a = (t >= o) ? s[t - o] : 0;
        __syncthreads();
        s[t] += a;
        __syncthreads();
    }
    if (i < n) offs[i + 1] = s[t];
    if (t == 1023) bsum[blockIdx.x] = s[t];
    if (blockIdx.x == 0 && t == 0) offs[0] = 0;
}

__global__ void scan2(int* __restrict__ bsum, int nb) {
    __shared__ int s[1024];
    int t = threadIdx.x;
    s[t] = (t < nb) ? bsum[t] : 0;
    __syncthreads();
    for (int o = 1; o < 1024; o <<= 1) {
        int a = (t >= o) ? s[t - o] : 0;
        __syncthreads();
        s[t] += a;
        __syncthreads();
    }
    int ex = (t > 0) ? s[t - 1] : 0;
    if (t < nb) bsum[t] = ex;
}

__global__ void scan3(int* __restrict__ offs, int* __restrict__ cursor,
                      const int* __restrict__ bsum, int n) {
    int i = blockIdx.x * 1024 + threadIdx.x;
    if (i < n) {
        const int v = offs[i + 1] + bsum[blockIdx.x];
        offs[i + 1] = v;
        if (i + 1 < n) cursor[i + 1] = v;
        if (i == 0) cursor[0] = 0;
    }
}

// ---------------- CSR pass B: XCD-affine fill from segment-grouped pairs ----
__global__ __launch_bounds__(256) void seg_fill(
    const int* __restrict__ sdst, const int* __restrict__ ssrc,
    const int* __restrict__ segoff, int* __restrict__ cursor,
    int* __restrict__ adj) {
    const int seg    = blockIdx.x & 7;      // XCD-affine (round-robin mapping)
    const int chunk  = blockIdx.x >> 3;
    const int nchunk = gridDim.x >> 3;
    const int lo0 = segoff[seg], hi0 = segoff[seg + 1];
    const int sz  = hi0 - lo0;
    const int per = (sz + nchunk - 1) / nchunk;
    const int lo  = lo0 + chunk * per;
    const int hi  = min(lo + per, hi0);
    for (int e = lo + threadIdx.x; e < hi; e += 256) {
        const int d   = sdst[e];
        const int pos = atomicAdd(&cursor[d], 1);
        adj[pos] = ssrc[e];
    }
}

// ---------------- fp32 -> bf16 (RNE) cast, 8 elems/thread ----------------
__global__ __launch_bounds__(256) void cast_bf16(
    const float* __restrict__ in, unsigned short* __restrict__ outb, long long n8) {
    const long long t = (long long)blockIdx.x * 256 + threadIdx.x;
    if (t >= n8) return;
    const float4 v0 = *reinterpret_cast<const float4*>(in + t * 8);
    const float4 v1 = *reinterpret_cast<const float4*>(in + t * 8 + 4);
    uint4 o;
    o.x = rne_bf16(v0.x) | (rne_bf16(v0.y) << 16);
    o.y = rne_bf16(v0.z) | (rne_bf16(v0.w) << 16);
    o.z = rne_bf16(v1.x) | (rne_bf16(v1.y) << 16);
    o.w = rne_bf16(v1.z) | (rne_bf16(v1.w) << 16);
    *reinterpret_cast<uint4*>(outb + t * 8) = o;
}

// ---------------- gather-mean from bf16 rows (8 threads/node) --------------
__global__ __launch_bounds__(256) void aggregate_bf16(
    const unsigned short* __restrict__ xb, float* __restrict__ agg,
    const int* __restrict__ offs, const int* __restrict__ adj, int n) {
    const int t  = blockIdx.x * 256 + threadIdx.x;
    const int nd = t >> 3;
    const int c8 = (t & 7) * 8;
    if (nd >= n) return;

    const int s = offs[nd];
    const int e = offs[nd + 1];

    float a0[8], a1[8], a2[8], a3[8];
#pragma unroll
    for (int p = 0; p < 8; ++p) { a0[p] = 0.f; a1[p] = 0.f; a2[p] = 0.f; a3[p] = 0.f; }

#define ACC8(A, U)                                                             \
    do {                                                                       \
        A[0] += __uint_as_float((U).x << 16);                                  \
        A[1] += __uint_as_float((U).x & 0xFFFF0000u);                          \
        A[2] += __uint_as_float((U).y << 16);                                  \
        A[3] += __uint_as_float((U).y & 0xFFFF0000u);                          \
        A[4] += __uint_as_float((U).z << 16);                                  \
        A[5] += __uint_as_float((U).z & 0xFFFF0000u);                          \
        A[6] += __uint_as_float((U).w << 16);                                  \
        A[7] += __uint_as_float((U).w & 0xFFFF0000u);                          \
    } while (0)

    int j = s;
    for (; j + 4 <= e; j += 4) {
        const int i0 = adj[j], i1 = adj[j + 1], i2 = adj[j + 2], i3 = adj[j + 3];
        const uint4 u0 = *reinterpret_cast<const uint4*>(xb + (size_t)i0 * DD + c8);
        const uint4 u1 = *reinterpret_cast<const uint4*>(xb + (size_t)i1 * DD + c8);
        const uint4 u2 = *reinterpret_cast<const uint4*>(xb + (size_t)i2 * DD + c8);
        const uint4 u3 = *reinterpret_cast<const uint4*>(xb + (size_t)i3 * DD + c8);
        ACC8(a0, u0); ACC8(a1, u1); ACC8(a2, u2); ACC8(a3, u3);
    }
    for (; j < e; ++j) {
        const uint4 u = *reinterpret_cast<const uint4*>(xb + (size_t)adj[j] * DD + c8);
        ACC8(a0, u);
    }
#undef ACC8

    const int deg = e - s;
    const float inv = (deg > 0) ? (1.0f / (float)deg) : 1.0f;
    float4 r0, r1;
    r0.x = (a0[0] + a1[0] + a2[0] + a3[0]) * inv;
    r0.y = (a0[1] + a1[1] + a2[1] + a3[1]) * inv;
    r0.z = (a0[2] + a1[2] + a2[2] + a3[2]) * inv;
    r0.w = (a0[3] + a1[3] + a2[3] + a3[3]) * inv;
    r1.x = (a0[4] + a1[4] + a2[4] + a3[4]) * inv;
    r1.y = (a0[5] + a1[5] + a2[5] + a3[5]) * inv;
    r1.z = (a0[6] + a1[6] + a2[6] + a3[6]) * inv;
    r1.w = (a0[7] + a1[7] + a2[7] + a3[7]) * inv;
    *reinterpret_cast<float4*>(agg + (size_t)nd * DD + c8)     = r0;
    *reinterpret_cast<float4*>(agg + (size_t)nd * DD + c8 + 4) = r1;
}

// ---------------- fp32 gather fallback (16 threads/node) ----------------
__global__ __launch_bounds__(256) void aggregate(
    const float* __restrict__ xin, float* __restrict__ agg,
    const int* __restrict__ offs, const int* __restrict__ adj, int n) {
    const int t  = blockIdx.x * 256 + threadIdx.x;
    const int nd = t >> 4;
    const int c  = (t & 15) * 4;
    if (nd >= n) return;
    const int s = offs[nd];
    const int e = offs[nd + 1];
    float4 a0 = {0.f, 0.f, 0.f, 0.f};
    float4 a1 = {0.f, 0.f, 0.f, 0.f};
    float4 a2 = {0.f, 0.f, 0.f, 0.f};
    float4 a3 = {0.f, 0.f, 0.f, 0.f};
    int j = s;
    for (; j + 4 <= e; j += 4) {
        const int i0 = adj[j], i1 = adj[j + 1], i2 = adj[j + 2], i3 = adj[j + 3];
        const float4 v0 = *reinterpret_cast<const float4*>(xin + (size_t)i0 * DD + c);
        const float4 v1 = *reinterpret_cast<const float4*>(xin + (size_t)i1 * DD + c);
        const float4 v2 = *reinterpret_cast<const float4*>(xin + (size_t)i2 * DD + c);
        const float4 v3 = *reinterpret_cast<const float4*>(xin + (size_t)i3 * DD + c);
        a0.x += v0.x; a0.y += v0.y; a0.z += v0.z; a0.w += v0.w;
        a1.x += v1.x; a1.y += v1.y; a1.z += v1.z; a1.w += v1.w;
        a2.x += v2.x; a2.y += v2.y; a2.z += v2.z; a2.w += v2.w;
        a3.x += v3.x; a3.y += v3.y; a3.z += v3.z; a3.w += v3.w;
    }
    for (; j < e; ++j) {
        const float4 v = *reinterpret_cast<const float4*>(xin + (size_t)adj[j] * DD + c);
        a0.x += v.x; a0.y += v.y; a0.z += v.z; a0.w += v.w;
    }
    const int deg = e - s;
    const float inv = (deg > 0) ? (1.0f / (float)deg) : 1.0f;
    float4 r;
    r.x = (a0.x + a1.x + a2.x + a3.x) * inv;
    r.y = (a0.y + a1.y + a2.y + a3.y) * inv;
    r.z = (a0.z + a1.z + a2.z + a3.z) * inv;
    r.w = (a0.w + a1.w + a2.w + a3.w) * inv;
    *reinterpret_cast<float4*>(agg + (size_t)nd * DD + c) = r;
}

// ---------------- W pre-pack into MFMA B-fragment layout, bf16 hi/lo --------
__global__ void pack_B(const float* __restrict__ Wl, const float* __restrict__ Wr,
                       unsigned* __restrict__ Bp, int L) {
    int t = blockIdx.x * 256 + threadIdx.x;
    int wv = t >> 6, lane = t & 63;
    if (wv >= L * 16) return;
    int layer = wv >> 4;
    int fid = wv & 15;
    int ks = fid >> 2, nt = fid & 3;
    int j = nt * 16 + (lane & 15);
    int kb = ks * 32 + (lane >> 4) * 8;
    const float* wl = Wl + (size_t)layer * DD * DD;
    const float* wr = Wr + (size_t)layer * DD * DD;
    unsigned hi[8], lo[8];
#pragma unroll
    for (int s = 0; s < 8; ++s) {
        int k = kb + s;
        float v = (k < DD) ? wl[k * DD + j] : wr[(k - DD) * DD + j];
        unsigned u = __float_as_uint(v);
        unsigned h = u & 0xFFFF0000u;
        hi[s] = h;
        float lf = v - __uint_as_float(h);         // exact residual
        lo[s] = __float_as_uint(lf) & 0xFFFF0000u;
    }
    size_t base_hi = ((size_t)(layer * 2 + 0) * 16 + fid) * 64 + lane;
    size_t base_lo = ((size_t)(layer * 2 + 1) * 16 + fid) * 64 + lane;
#pragma unroll
    for (int p = 0; p < 4; ++p) {
        Bp[base_hi * 4 + p] = (hi[2 * p] >> 16) | hi[2 * p + 1];
        Bp[base_lo * 4 + p] = (lo[2 * p] >> 16) | lo[2 * p + 1];
    }
}

// ---------------- layer GEMM + optional bf16 copy of the output -------------
__global__ __launch_bounds__(256, 2) void mfma_gemm(
    const float* __restrict__ g, const float* __restrict__ x,
    float* __restrict__ out, unsigned short* __restrict__ outb,   // may be null
    const unsigned* __restrict__ Bp, const float* __restrict__ bias, int n) {
    const int lane = threadIdx.x & 63;
    const int wv   = (int)((blockIdx.x * 256 + threadIdx.x) >> 6);
    const int nwv  = (int)((gridDim.x * 256) >> 6);

    short8 Bh[4][4], Bl[4][4];
#pragma unroll
    for (int ks = 0; ks < 4; ++ks)
#pragma unroll
        for (int nt = 0; nt < 4; ++nt) {
            int fid = ks * 4 + nt;
            const uint4 h = *reinterpret_cast<const uint4*>(Bp + ((size_t)fid * 64 + lane) * 4);
            const uint4 l = *reinterpret_cast<const uint4*>(Bp + ((size_t)(16 + fid) * 64 + lane) * 4);
            Bh[ks][nt] = pack4(h.x, h.y, h.z, h.w);
            Bl[ks][nt] = pack4(l.x, l.y, l.z, l.w);
        }

    float bv[4];
#pragma unroll
    for (int nt = 0; nt < 4; ++nt) bv[nt] = bias[nt * 16 + (lane & 15)];

    const int ntiles = (n + 15) >> 4;
    for (int tile = wv; tile < ntiles; tile += nwv) {
        const int row = tile * 16 + (lane & 15);
        const bool ok = row < n;
        const float* grow = g + (size_t)row * DD + (lane >> 4) * 8;
        const float* xrow = x + (size_t)row * DD + (lane >> 4) * 8;

        f32x4 acc[4];
#pragma unroll
        for (int nt = 0; nt < 4; ++nt) acc[nt] = (f32x4){bv[nt], bv[nt], bv[nt], bv[nt]};

#pragma unroll
        for (int ks = 0; ks < 4; ++ks) {
            const float* base = ((ks < 2) ? grow : xrow) + (ks & 1) * 32;
            f32x4 v0 = ok ? *reinterpret_cast<const f32x4*>(base)
                          : (f32x4){0.f, 0.f, 0.f, 0.f};
            f32x4 v1 = ok ? *reinterpret_cast<const f32x4*>(base + 4)
                          : (f32x4){0.f, 0.f, 0.f, 0.f};
            float vv[8] = {v0[0], v0[1], v0[2], v0[3], v1[0], v1[1], v1[2], v1[3]};
            unsigned hu[4], lu[4];
#pragma unroll
            for (int p = 0; p < 4; ++p) {
                unsigned ua = __float_as_uint(vv[2 * p]);
                unsigned ub = __float_as_uint(vv[2 * p + 1]);
                unsigned ha = ua & 0xFFFF0000u, hb = ub & 0xFFFF0000u;
                hu[p] = (ha >> 16) | hb;
                float la = vv[2 * p]     - __uint_as_float(ha);
                float lb = vv[2 * p + 1] - __uint_as_float(hb);
                lu[p] = ((__float_as_uint(la) & 0xFFFF0000u) >> 16) |
                        (__float_as_uint(lb) & 0xFFFF0000u);
            }
            const short8 Ah = pack4(hu[0], hu[1], hu[2], hu[3]);
            const short8 Al = pack4(lu[0], lu[1], lu[2], lu[3]);
#pragma unroll
            for (int nt = 0; nt < 4; ++nt) {
                acc[nt] = __builtin_amdgcn_mfma_f32_16x16x32_bf16(Ah, Bh[ks][nt], acc[nt], 0, 0, 0);
                acc[nt] = __builtin_amdgcn_mfma_f32_16x16x32_bf16(Al, Bh[ks][nt], acc[nt], 0, 0, 0);
                acc[nt] = __builtin_amdgcn_mfma_f32_16x16x32_bf16(Ah, Bl[ks][nt], acc[nt], 0, 0, 0);
            }
        }

        // C/D layout (verified): col = lane&15, row = (lane>>4)*4 + reg
        const int r0 = tile * 16 + (lane >> 4) * 4;
#pragma unroll
        for (int r = 0; r < 4; ++r) {
            const int rr = r0 + r;
            if (rr < n) {
#pragma unroll
                for (int nt = 0; nt < 4; ++nt) {
                    const float v = acc[nt][r];
                    const size_t idx = (size_t)rr * DD + nt * 16 + (lane & 15);
                    out[idx] = v;
                    if (outb) outb[idx] = (unsigned short)rne_bf16(v);
                }
            }
        }
    }
}

// ---------------- pooling partials over TWO arrays at once ----------------
__global__ __launch_bounds__(256) void pool_partial2(
    const float* __restrict__ xa, const float* __restrict__ xb,
    const int* __restrict__ batch,
    float* __restrict__ sumsA, float* __restrict__ sumsB, int n) {
    const int lane = threadIdx.x & 63;
    const int wv   = (int)((blockIdx.x * blockDim.x + threadIdx.x) >> 6);
    const int nwv  = (int)((gridDim.x * blockDim.x) >> 6);
    const int chunk = (n + nwv - 1) / nwv;
    const int start = wv * chunk;
    if (start >= n) return;
    const int end = min(start + chunk, n);

    int g = batch[start];
    float accA = 0.f, accB = 0.f;
    for (int nd = start; nd < end; ++nd) {
        const int bg = batch[nd];
        if (bg != g) {
            atomicAdd(&sumsA[(size_t)g * DD + lane], accA);
            atomicAdd(&sumsB[(size_t)g * DD + lane], accB);
            accA = 0.f; accB = 0.f;
            g = bg;
        }
        accA += xa[(size_t)nd * DD + lane];
        accB += xb[(size_t)nd * DD + lane];
    }
    atomicAdd(&sumsA[(size_t)g * DD + lane], accA);
    atomicAdd(&sumsB[(size_t)g * DD + lane], accB);
}

// ---------------- final: out[g] = mean(agg3)@Wl + mean(x2)@Wr + b ----------
__global__ void final_gemm(const float* __restrict__ sumsA, const float* __restrict__ sumsX,
                           const int* __restrict__ batch,
                           const float* __restrict__ Wl, const float* __restrict__ bl,
                           const float* __restrict__ Wr,
                           float* __restrict__ out, int n) {
    const int g = blockIdx.x;
    const int d = threadIdx.x;  // 64 threads

    int lo = 0, hi = n;
    while (lo < hi) { int m = (lo + hi) >> 1; if (batch[m] < g) lo = m + 1; else hi = m; }
    const int st = lo;
    lo = 0; hi = n;
    while (lo < hi) { int m = (lo + hi) >> 1; if (batch[m] < g + 1) lo = m + 1; else hi = m; }
    const int c = lo - st;

    if (c == 0) {                    // reference: empty graph -> 0 (not bias)
        out[(size_t)g * DD + d] = 0.f;
        return;
    }
    const float inv = 1.0f / (float)c;

    __shared__ float sa[DD], sx[DD];
    sa[d] = sumsA[(size_t)g * DD + d] * inv;
    sx[d] = sumsX[(size_t)g * DD + d] * inv;
    __syncthreads();

    float acc = bl[d];
#pragma unroll 8
    for (int k = 0; k < DD; ++k) acc += sa[k] * Wl[k * DD + d];
#pragma unroll 8
    for (int k = 0; k < DD; ++k) acc += sx[k] * Wr[k * DD + d];
    out[(size_t)g * DD + d] = acc;
}

extern "C" void kernel_launch(void* const* d_in, const int* in_sizes, int n_in,
                              void* d_out, int out_size, void* d_ws, size_t ws_size,
                              hipStream_t stream) {
    const float* x     = (const float*)d_in[0];
    const int*   ei    = (const int*)d_in[1];
    const int*   batch = (const int*)d_in[2];
    const float* Wl    = (const float*)d_in[3];
    const float* bl    = (const float*)d_in[4];
    const float* Wr    = (const float*)d_in[5];

    const int N = in_sizes[0] / DD;
    const int E = in_sizes[1] / 2;
    const int L = in_sizes[3] / (DD * DD);
    const int G = out_size / DD;
    const int segsz = (N + NSEG - 1) / NSEG;

    const int* src = ei;        // edge_index[0]
    const int* dst = ei + E;    // edge_index[1]

    char* ws = (char*)d_ws;
    size_t off = 0;
    auto alloc = [&](size_t bytes) -> char* {
        char* p = ws + off;
        off += (bytes + 255) & ~(size_t)255;
        return p;
    };
    int*      deg    = (int*)alloc((size_t)N * 4);
    int*      offs   = (int*)alloc((size_t)(N + 1) * 4);
    int*      cursor = (int*)alloc((size_t)N * 4);
    int*      adj    = (int*)alloc((size_t)E * 4);
    int*      bsum   = (int*)alloc(1024 * 4);
    int*      cnt    = (int*)alloc((size_t)ABLK * NSEG * 4);
    int*      basep  = (int*)alloc((size_t)ABLK * NSEG * 4);
    int*      segoff = (int*)alloc((NSEG + 1) * 4);
    float*    b0     = (float*)alloc((size_t)N * DD * 4);
    float*    b1     = (float*)alloc((size_t)N * DD * 4);
    float*    aggbuf = (float*)alloc((size_t)N * DD * 4);
    unsigned* Bp     = (unsigned*)alloc((size_t)L * 2 * 16 * 64 * 4 * 4);
    float*    sumsA  = (float*)alloc((size_t)G * DD * 4);
    float*    sumsX  = (float*)alloc((size_t)G * DD * 4);
    const size_t bfbytes = (size_t)N * DD * 2;
    unsigned short* bfA = (unsigned short*)alloc(bfbytes);
    unsigned short* bfB = (unsigned short*)alloc(bfbytes);
    const bool use_bf16 = (off <= ws_size);

    // sdst/ssrc alias b0 (dead until first mfma_gemm, which is stream-ordered
    // after seg_fill): 2*E ints = 8MB <= N*DD*4 = 25.6MB.
    int* sdst = (int*)b0;
    int* ssrc = sdst + E;

    // ---- CSR build: private-region partition + XCD-local fill ----
    hipMemsetAsync(deg, 0, (size_t)N * 4, stream);
    seg_count<<<ABLK, 256, 0, stream>>>(dst, deg, cnt, E, segsz);
    seg_base<<<1, 256, 0, stream>>>(cnt, basep, segoff, E);
    const int nb = (N + 1023) / 1024;
    scan1<<<nb, 1024, 0, stream>>>(deg, offs, bsum, N);
    scan2<<<1, 1024, 0, stream>>>(bsum, nb);
    scan3<<<nb, 1024, 0, stream>>>(offs, cursor, bsum, N);
    seg_scatter<<<ABLK, 256, 0, stream>>>(src, dst, basep, sdst, ssrc, E, segsz);
    seg_fill<<<2048, 256, 0, stream>>>(sdst, ssrc, segoff, cursor, adj);

    // ---- pack W into MFMA fragment layout (all layers) ----
    pack_B<<<(L * 16 * 64 + 255) / 256, 256, 0, stream>>>(Wl, Wr, Bp, L);

    // ---- layers 0..L-2: aggregate + MFMA gemm (ping-pong) ----
    const float* cur = x;
    float* bufs[2] = {b0, b1};
    unsigned short* bfs[2] = {bfB, bfA};   // gemm layer l writes bfs[l&1]
    const unsigned short* curb = bfA;      // bf16 view of cur

    if (use_bf16) {
        const long long n8 = (long long)N * DD / 8;
        cast_bf16<<<(int)((n8 + 255) / 256), 256, 0, stream>>>(x, bfA, n8);
    }

    const int aggB_blocks = (N * 8 + 255) / 256;
    const int aggF_blocks = (N * 16 + 255) / 256;
    for (int l = 0; l < L - 1; ++l) {
        float* outb = bufs[l & 1];
        if (use_bf16) {
            aggregate_bf16<<<aggB_blocks, 256, 0, stream>>>(curb, aggbuf, offs, adj, N);
        } else {
            aggregate<<<aggF_blocks, 256, 0, stream>>>(cur, aggbuf, offs, adj, N);
        }
        mfma_gemm<<<1024, 256, 0, stream>>>(aggbuf, cur, outb,
                                            use_bf16 ? bfs[l & 1] : (unsigned short*)nullptr,
                                            Bp + (size_t)l * 2 * 16 * 64 * 4,
                                            bl + (size_t)l * DD, N);
        cur = outb;
        curb = bfs[l & 1];
    }

    // ---- last layer: pooling is linear -> pool(agg), pool(x), tiny GEMM ----
    if (use_bf16) {
        aggregate_bf16<<<aggB_blocks, 256, 0, stream>>>(curb, aggbuf, offs, adj, N);
    } else {
        aggregate<<<aggF_blocks, 256, 0, stream>>>(cur, aggbuf, offs, adj, N);
    }
    hipMemsetAsync(sumsA, 0, (size_t)G * DD * 4, stream);
    hipMemsetAsync(sumsX, 0, (size_t)G * DD * 4, stream);
    pool_partial2<<<2048, 256, 0, stream>>>(aggbuf, cur, batch, sumsA, sumsX, N);
    final_gemm<<<G, DD, 0, stream>>>(sumsA, sumsX, batch,
                                     Wl + (size_t)(L - 1) * DD * DD,
                                     bl + (size_t)(L - 1) * DD,
                                     Wr + (size_t)(L - 1) * DD * DD,
                                     (float*)d_out, N);
}

// Round 10
// 231.010 us; speedup vs baseline: 2.0566x; 1.1935x over previous
//
#include <hip/hip_runtime.h>

// GraphSAGE (mean) x3 + per-graph mean pool, MI355X.
// R10: CSR build = single-level counting sort with ONLY coalesced global
// writes. R6-R9 established that scattered 4B stores cost ~9-10x write
// amplification no matter the L2 residency engineering (partial-line
// writebacks). Pipeline: per-block bucket histogram -> exact private ranges
// (no global atomics) -> packed scatter into 80B block-private runs ->
// per-bucket LDS counting sort emitting offs AND adj fully coalesced.
// Replaces deg histogram + 3 scans + cursor + fill entirely.
// Packing (d&255)<<24|src requires N < 2^24 (here N=100k).

#define DD 64
#define NBA 128    // blocks in count/scatter passes
#define CAP 4096   // per-bucket LDS sort capacity (avg bucket ~2560 edges)

typedef __attribute__((ext_vector_type(8))) short short8;   // 8 bf16 (4 VGPRs)
typedef __attribute__((ext_vector_type(4))) float f32x4;    // MFMA accumulator

__device__ inline short8 pack4(unsigned a, unsigned b, unsigned c, unsigned d) {
    union { uint4 u; short8 s; } un;
    un.u = make_uint4(a, b, c, d);
    return un.s;
}

__device__ inline unsigned rne_bf16(float v) {   // round-to-nearest-even, high16
    unsigned u = __float_as_uint(v);
    return (u + 0x7FFFu + ((u >> 16) & 1u)) >> 16;
}

// ---------------- CSR 1: per-block bucket histogram (LDS, coalesced out) ----
__global__ __launch_bounds__(256) void bucket_count(
    const int* __restrict__ dst, int* __restrict__ cnt, int E, int NBUCK) {
    extern __shared__ int hist[];   // NBUCK ints
    const int b = blockIdx.x;
    const int per = (E + NBA - 1) / NBA;
    const int lo = b * per, hi = min(lo + per, E);
    for (int k = threadIdx.x; k < NBUCK; k += 256) hist[k] = 0;
    __syncthreads();
    for (int e = lo + threadIdx.x; e < hi; e += 256)
        atomicAdd(&hist[dst[e] >> 8], 1);
    __syncthreads();
    for (int k = threadIdx.x; k < NBUCK; k += 256)
        cnt[b * NBUCK + k] = hist[k];
}

// ---------------- CSR 2: exact private ranges (single block) ----------------
// base[b][k] = boff[k] + sum_{b'<b} cnt[b'][k];  boff = excl-scan of totals.
__global__ __launch_bounds__(1024) void bucket_base(
    const int* __restrict__ cnt, int* __restrict__ base,
    int* __restrict__ boff, int* __restrict__ offs, int NBUCK, int E, int N) {
    __shared__ int s[1024];
    const int t = threadIdx.x;
    int tot = 0;
    if (t < NBUCK) {
        for (int b = 0; b < NBA; ++b) {
            base[b * NBUCK + t] = tot;
            tot += cnt[b * NBUCK + t];
        }
    }
    s[t] = tot;
    __syncthreads();
    for (int o = 1; o < 1024; o <<= 1) {
        int a = (t >= o) ? s[t - o] : 0;
        __syncthreads();
        s[t] += a;
        __syncthreads();
    }
    const int ex = (t > 0) ? s[t - 1] : 0;
    if (t < NBUCK) {
        boff[t] = ex;
        for (int b = 0; b < NBA; ++b) base[b * NBUCK + t] += ex;
    }
    if (t == 0) { boff[NBUCK] = E; offs[N] = E; }
}

// ---------------- CSR 3: packed scatter into block-private runs -------------
__global__ __launch_bounds__(256) void bucket_scatter(
    const int* __restrict__ src, const int* __restrict__ dst,
    const int* __restrict__ base, unsigned* __restrict__ ebuf,
    int E, int NBUCK) {
    extern __shared__ int pos[];   // NBUCK ints
    const int b = blockIdx.x;
    const int per = (E + NBA - 1) / NBA;
    const int lo = b * per, hi = min(lo + per, E);
    for (int k = threadIdx.x; k < NBUCK; k += 256) pos[k] = base[b * NBUCK + k];
    __syncthreads();
    for (int e = lo + threadIdx.x; e < hi; e += 256) {
        const int d = dst[e];
        const int s = src[e];
        const int p = atomicAdd(&pos[d >> 8], 1);          // LDS only
        ebuf[p] = ((unsigned)(d & 255) << 24) | (unsigned)s;
    }
}

// ---------------- CSR 4: per-bucket LDS counting sort -----------------------
// Emits offs (coalesced) and adj (coalesced). One block per 256-node bucket.
__global__ __launch_bounds__(256) void bucket_sort(
    const unsigned* __restrict__ ebuf, const int* __restrict__ boff,
    int* __restrict__ offs, int* __restrict__ adj, int N) {
    const int b  = blockIdx.x;
    const int lo = boff[b];
    const int sz = boff[b + 1] - lo;
    const int base = b << 8;
    const int t = threadIdx.x;

    __shared__ int hist[256];
    __shared__ int hcur[256];
    __shared__ unsigned sbuf[CAP];

    hist[t] = 0;
    __syncthreads();
    for (int i = t; i < sz; i += 256)
        atomicAdd(&hist[ebuf[lo + i] >> 24], 1);
    __syncthreads();
    // exclusive scan of hist (Hillis-Steele over 256)
    int v = hist[t];
    hcur[t] = v;
    __syncthreads();
    for (int o = 1; o < 256; o <<= 1) {
        int a = (t >= o) ? hcur[t - o] : 0;
        __syncthreads();
        hcur[t] += a;
        __syncthreads();
    }
    const int ex = hcur[t] - v;      // exclusive
    __syncthreads();
    hcur[t] = ex;
    if (base + t < N) offs[base + t] = lo + ex;
    __syncthreads();

    if (sz <= CAP) {
        for (int i = t; i < sz; i += 256) {
            const unsigned w = ebuf[lo + i];
            const int p = atomicAdd(&hcur[w >> 24], 1);
            sbuf[p] = w & 0x00FFFFFFu;
        }
        __syncthreads();
        for (int i = t; i < sz; i += 256) adj[lo + i] = (int)sbuf[i];   // coalesced
    } else {                          // skew fallback (correct, uncoalesced)
        for (int i = t; i < sz; i += 256) {
            const unsigned w = ebuf[lo + i];
            const int p = atomicAdd(&hcur[w >> 24], 1);
            adj[lo + p] = (int)(w & 0x00FFFFFFu);
        }
    }
}

// ---------------- fp32 -> bf16 (RNE) cast, 8 elems/thread ----------------
__global__ __launch_bounds__(256) void cast_bf16(
    const float* __restrict__ in, unsigned short* __restrict__ outb, long long n8) {
    const long long t = (long long)blockIdx.x * 256 + threadIdx.x;
    if (t >= n8) return;
    const float4 v0 = *reinterpret_cast<const float4*>(in + t * 8);
    const float4 v1 = *reinterpret_cast<const float4*>(in + t * 8 + 4);
    uint4 o;
    o.x = rne_bf16(v0.x) | (rne_bf16(v0.y) << 16);
    o.y = rne_bf16(v0.z) | (rne_bf16(v0.w) << 16);
    o.z = rne_bf16(v1.x) | (rne_bf16(v1.y) << 16);
    o.w = rne_bf16(v1.z) | (rne_bf16(v1.w) << 16);
    *reinterpret_cast<uint4*>(outb + t * 8) = o;
}

// ---------------- gather-mean from bf16 rows (8 threads/node) --------------
__global__ __launch_bounds__(256) void aggregate_bf16(
    const unsigned short* __restrict__ xb, float* __restrict__ agg,
    const int* __restrict__ offs, const int* __restrict__ adj, int n) {
    const int t  = blockIdx.x * 256 + threadIdx.x;
    const int nd = t >> 3;
    const int c8 = (t & 7) * 8;
    if (nd >= n) return;

    const int s = offs[nd];
    const int e = offs[nd + 1];

    float a0[8], a1[8], a2[8], a3[8];
#pragma unroll
    for (int p = 0; p < 8; ++p) { a0[p] = 0.f; a1[p] = 0.f; a2[p] = 0.f; a3[p] = 0.f; }

#define ACC8(A, U)                                                             \
    do {                                                                       \
        A[0] += __uint_as_float((U).x << 16);                                  \
        A[1] += __uint_as_float((U).x & 0xFFFF0000u);                          \
        A[2] += __uint_as_float((U).y << 16);                                  \
        A[3] += __uint_as_float((U).y & 0xFFFF0000u);                          \
        A[4] += __uint_as_float((U).z << 16);                                  \
        A[5] += __uint_as_float((U).z & 0xFFFF0000u);                          \
        A[6] += __uint_as_float((U).w << 16);                                  \
        A[7] += __uint_as_float((U).w & 0xFFFF0000u);                          \
    } while (0)

    int j = s;
    for (; j + 4 <= e; j += 4) {
        const int i0 = adj[j], i1 = adj[j + 1], i2 = adj[j + 2], i3 = adj[j + 3];
        const uint4 u0 = *reinterpret_cast<const uint4*>(xb + (size_t)i0 * DD + c8);
        const uint4 u1 = *reinterpret_cast<const uint4*>(xb + (size_t)i1 * DD + c8);
        const uint4 u2 = *reinterpret_cast<const uint4*>(xb + (size_t)i2 * DD + c8);
        const uint4 u3 = *reinterpret_cast<const uint4*>(xb + (size_t)i3 * DD + c8);
        ACC8(a0, u0); ACC8(a1, u1); ACC8(a2, u2); ACC8(a3, u3);
    }
    for (; j < e; ++j) {
        const uint4 u = *reinterpret_cast<const uint4*>(xb + (size_t)adj[j] * DD + c8);
        ACC8(a0, u);
    }
#undef ACC8

    const int deg = e - s;
    const float inv = (deg > 0) ? (1.0f / (float)deg) : 1.0f;
    float4 r0, r1;
    r0.x = (a0[0] + a1[0] + a2[0] + a3[0]) * inv;
    r0.y = (a0[1] + a1[1] + a2[1] + a3[1]) * inv;
    r0.z = (a0[2] + a1[2] + a2[2] + a3[2]) * inv;
    r0.w = (a0[3] + a1[3] + a2[3] + a3[3]) * inv;
    r1.x = (a0[4] + a1[4] + a2[4] + a3[4]) * inv;
    r1.y = (a0[5] + a1[5] + a2[5] + a3[5]) * inv;
    r1.z = (a0[6] + a1[6] + a2[6] + a3[6]) * inv;
    r1.w = (a0[7] + a1[7] + a2[7] + a3[7]) * inv;
    *reinterpret_cast<float4*>(agg + (size_t)nd * DD + c8)     = r0;
    *reinterpret_cast<float4*>(agg + (size_t)nd * DD + c8 + 4) = r1;
}

// ---------------- fp32 gather fallback (16 threads/node) ----------------
__global__ __launch_bounds__(256) void aggregate(
    const float* __restrict__ xin, float* __restrict__ agg,
    const int* __restrict__ offs, const int* __restrict__ adj, int n) {
    const int t  = blockIdx.x * 256 + threadIdx.x;
    const int nd = t >> 4;
    const int c  = (t & 15) * 4;
    if (nd >= n) return;
    const int s = offs[nd];
    const int e = offs[nd + 1];
    float4 a0 = {0.f, 0.f, 0.f, 0.f};
    float4 a1 = {0.f, 0.f, 0.f, 0.f};
    float4 a2 = {0.f, 0.f, 0.f, 0.f};
    float4 a3 = {0.f, 0.f, 0.f, 0.f};
    int j = s;
    for (; j + 4 <= e; j += 4) {
        const int i0 = adj[j], i1 = adj[j + 1], i2 = adj[j + 2], i3 = adj[j + 3];
        const float4 v0 = *reinterpret_cast<const float4*>(xin + (size_t)i0 * DD + c);
        const float4 v1 = *reinterpret_cast<const float4*>(xin + (size_t)i1 * DD + c);
        const float4 v2 = *reinterpret_cast<const float4*>(xin + (size_t)i2 * DD + c);
        const float4 v3 = *reinterpret_cast<const float4*>(xin + (size_t)i3 * DD + c);
        a0.x += v0.x; a0.y += v0.y; a0.z += v0.z; a0.w += v0.w;
        a1.x += v1.x; a1.y += v1.y; a1.z += v1.z; a1.w += v1.w;
        a2.x += v2.x; a2.y += v2.y; a2.z += v2.z; a2.w += v2.w;
        a3.x += v3.x; a3.y += v3.y; a3.z += v3.z; a3.w += v3.w;
    }
    for (; j < e; ++j) {
        const float4 v = *reinterpret_cast<const float4*>(xin + (size_t)adj[j] * DD + c);
        a0.x += v.x; a0.y += v.y; a0.z += v.z; a0.w += v.w;
    }
    const int deg = e - s;
    const float inv = (deg > 0) ? (1.0f / (float)deg) : 1.0f;
    float4 r;
    r.x = (a0.x + a1.x + a2.x + a3.x) * inv;
    r.y = (a0.y + a1.y + a2.y + a3.y) * inv;
    r.z = (a0.z + a1.z + a2.z + a3.z) * inv;
    r.w = (a0.w + a1.w + a2.w + a3.w) * inv;
    *reinterpret_cast<float4*>(agg + (size_t)nd * DD + c) = r;
}

// ---------------- W pre-pack into MFMA B-fragment layout, bf16 hi/lo --------
__global__ void pack_B(const float* __restrict__ Wl, const float* __restrict__ Wr,
                       unsigned* __restrict__ Bp, int L) {
    int t = blockIdx.x * 256 + threadIdx.x;
    int wv = t >> 6, lane = t & 63;
    if (wv >= L * 16) return;
    int layer = wv >> 4;
    int fid = wv & 15;
    int ks = fid >> 2, nt = fid & 3;
    int j = nt * 16 + (lane & 15);
    int kb = ks * 32 + (lane >> 4) * 8;
    const float* wl = Wl + (size_t)layer * DD * DD;
    const float* wr = Wr + (size_t)layer * DD * DD;
    unsigned hi[8], lo[8];
#pragma unroll
    for (int s = 0; s < 8; ++s) {
        int k = kb + s;
        float v = (k < DD) ? wl[k * DD + j] : wr[(k - DD) * DD + j];
        unsigned u = __float_as_uint(v);
        unsigned h = u & 0xFFFF0000u;
        hi[s] = h;
        float lf = v - __uint_as_float(h);         // exact residual
        lo[s] = __float_as_uint(lf) & 0xFFFF0000u;
    }
    size_t base_hi = ((size_t)(layer * 2 + 0) * 16 + fid) * 64 + lane;
    size_t base_lo = ((size_t)(layer * 2 + 1) * 16 + fid) * 64 + lane;
#pragma unroll
    for (int p = 0; p < 4; ++p) {
        Bp[base_hi * 4 + p] = (hi[2 * p] >> 16) | hi[2 * p + 1];
        Bp[base_lo * 4 + p] = (lo[2 * p] >> 16) | lo[2 * p + 1];
    }
}

// ---------------- layer GEMM + optional bf16 copy of the output -------------
__global__ __launch_bounds__(256, 2) void mfma_gemm(
    const float* __restrict__ g, const float* __restrict__ x,
    float* __restrict__ out, unsigned short* __restrict__ outb,   // may be null
    const unsigned* __restrict__ Bp, const float* __restrict__ bias, int n) {
    const int lane = threadIdx.x & 63;
    const int wv   = (int)((blockIdx.x * 256 + threadIdx.x) >> 6);
    const int nwv  = (int)((gridDim.x * 256) >> 6);

    short8 Bh[4][4], Bl[4][4];
#pragma unroll
    for (int ks = 0; ks < 4; ++ks)
#pragma unroll
        for (int nt = 0; nt < 4; ++nt) {
            int fid = ks * 4 + nt;
            const uint4 h = *reinterpret_cast<const uint4*>(Bp + ((size_t)fid * 64 + lane) * 4);
            const uint4 l = *reinterpret_cast<const uint4*>(Bp + ((size_t)(16 + fid) * 64 + lane) * 4);
            Bh[ks][nt] = pack4(h.x, h.y, h.z, h.w);
            Bl[ks][nt] = pack4(l.x, l.y, l.z, l.w);
        }

    float bv[4];
#pragma unroll
    for (int nt = 0; nt < 4; ++nt) bv[nt] = bias[nt * 16 + (lane & 15)];

    const int ntiles = (n + 15) >> 4;
    for (int tile = wv; tile < ntiles; tile += nwv) {
        const int row = tile * 16 + (lane & 15);
        const bool ok = row < n;
        const float* grow = g + (size_t)row * DD + (lane >> 4) * 8;
        const float* xrow = x + (size_t)row * DD + (lane >> 4) * 8;

        f32x4 acc[4];
#pragma unroll
        for (int nt = 0; nt < 4; ++nt) acc[nt] = (f32x4){bv[nt], bv[nt], bv[nt], bv[nt]};

#pragma unroll
        for (int ks = 0; ks < 4; ++ks) {
            const float* base = ((ks < 2) ? grow : xrow) + (ks & 1) * 32;
            f32x4 v0 = ok ? *reinterpret_cast<const f32x4*>(base)
                          : (f32x4){0.f, 0.f, 0.f, 0.f};
            f32x4 v1 = ok ? *reinterpret_cast<const f32x4*>(base + 4)
                          : (f32x4){0.f, 0.f, 0.f, 0.f};
            float vv[8] = {v0[0], v0[1], v0[2], v0[3], v1[0], v1[1], v1[2], v1[3]};
            unsigned hu[4], lu[4];
#pragma unroll
            for (int p = 0; p < 4; ++p) {
                unsigned ua = __float_as_uint(vv[2 * p]);
                unsigned ub = __float_as_uint(vv[2 * p + 1]);
                unsigned ha = ua & 0xFFFF0000u, hb = ub & 0xFFFF0000u;
                hu[p] = (ha >> 16) | hb;
                float la = vv[2 * p]     - __uint_as_float(ha);
                float lb = vv[2 * p + 1] - __uint_as_float(hb);
                lu[p] = ((__float_as_uint(la) & 0xFFFF0000u) >> 16) |
                        (__float_as_uint(lb) & 0xFFFF0000u);
            }
            const short8 Ah = pack4(hu[0], hu[1], hu[2], hu[3]);
            const short8 Al = pack4(lu[0], lu[1], lu[2], lu[3]);
#pragma unroll
            for (int nt = 0; nt < 4; ++nt) {
                acc[nt] = __builtin_amdgcn_mfma_f32_16x16x32_bf16(Ah, Bh[ks][nt], acc[nt], 0, 0, 0);
                acc[nt] = __builtin_amdgcn_mfma_f32_16x16x32_bf16(Al, Bh[ks][nt], acc[nt], 0, 0, 0);
                acc[nt] = __builtin_amdgcn_mfma_f32_16x16x32_bf16(Ah, Bl[ks][nt], acc[nt], 0, 0, 0);
            }
        }

        // C/D layout (verified): col = lane&15, row = (lane>>4)*4 + reg
        const int r0 = tile * 16 + (lane >> 4) * 4;
#pragma unroll
        for (int r = 0; r < 4; ++r) {
            const int rr = r0 + r;
            if (rr < n) {
#pragma unroll
                for (int nt = 0; nt < 4; ++nt) {
                    const float v = acc[nt][r];
                    const size_t idx = (size_t)rr * DD + nt * 16 + (lane & 15);
                    out[idx] = v;
                    if (outb) outb[idx] = (unsigned short)rne_bf16(v);
                }
            }
        }
    }
}

// ---------------- pooling partials over TWO arrays at once ----------------
__global__ __launch_bounds__(256) void pool_partial2(
    const float* __restrict__ xa, const float* __restrict__ xb,
    const int* __restrict__ batch,
    float* __restrict__ sumsA, float* __restrict__ sumsB, int n) {
    const int lane = threadIdx.x & 63;
    const int wv   = (int)((blockIdx.x * blockDim.x + threadIdx.x) >> 6);
    const int nwv  = (int)((gridDim.x * blockDim.x) >> 6);
    const int chunk = (n + nwv - 1) / nwv;
    const int start = wv * chunk;
    if (start >= n) return;
    const int end = min(start + chunk, n);

    int g = batch[start];
    float accA = 0.f, accB = 0.f;
    for (int nd = start; nd < end; ++nd) {
        const int bg = batch[nd];
        if (bg != g) {
            atomicAdd(&sumsA[(size_t)g * DD + lane], accA);
            atomicAdd(&sumsB[(size_t)g * DD + lane], accB);
            accA = 0.f; accB = 0.f;
            g = bg;
        }
        accA += xa[(size_t)nd * DD + lane];
        accB += xb[(size_t)nd * DD + lane];
    }
    atomicAdd(&sumsA[(size_t)g * DD + lane], accA);
    atomicAdd(&sumsB[(size_t)g * DD + lane], accB);
}

// ---------------- final: out[g] = mean(agg3)@Wl + mean(x2)@Wr + b ----------
__global__ void final_gemm(const float* __restrict__ sumsA, const float* __restrict__ sumsX,
                           const int* __restrict__ batch,
                           const float* __restrict__ Wl, const float* __restrict__ bl,
                           const float* __restrict__ Wr,
                           float* __restrict__ out, int n) {
    const int g = blockIdx.x;
    const int d = threadIdx.x;  // 64 threads

    int lo = 0, hi = n;
    while (lo < hi) { int m = (lo + hi) >> 1; if (batch[m] < g) lo = m + 1; else hi = m; }
    const int st = lo;
    lo = 0; hi = n;
    while (lo < hi) { int m = (lo + hi) >> 1; if (batch[m] < g + 1) lo = m + 1; else hi = m; }
    const int c = lo - st;

    if (c == 0) {                    // reference: empty graph -> 0 (not bias)
        out[(size_t)g * DD + d] = 0.f;
        return;
    }
    const float inv = 1.0f / (float)c;

    __shared__ float sa[DD], sx[DD];
    sa[d] = sumsA[(size_t)g * DD + d] * inv;
    sx[d] = sumsX[(size_t)g * DD + d] * inv;
    __syncthreads();

    float acc = bl[d];
#pragma unroll 8
    for (int k = 0; k < DD; ++k) acc += sa[k] * Wl[k * DD + d];
#pragma unroll 8
    for (int k = 0; k < DD; ++k) acc += sx[k] * Wr[k * DD + d];
    out[(size_t)g * DD + d] = acc;
}

extern "C" void kernel_launch(void* const* d_in, const int* in_sizes, int n_in,
                              void* d_out, int out_size, void* d_ws, size_t ws_size,
                              hipStream_t stream) {
    const float* x     = (const float*)d_in[0];
    const int*   ei    = (const int*)d_in[1];
    const int*   batch = (const int*)d_in[2];
    const float* Wl    = (const float*)d_in[3];
    const float* bl    = (const float*)d_in[4];
    const float* Wr    = (const float*)d_in[5];

    const int N = in_sizes[0] / DD;
    const int E = in_sizes[1] / 2;
    const int L = in_sizes[3] / (DD * DD);
    const int G = out_size / DD;
    const int NBUCK = (N + 255) >> 8;          // 256-node buckets (<=1024 for N<=262144)

    const int* src = ei;        // edge_index[0]
    const int* dst = ei + E;    // edge_index[1]

    char* ws = (char*)d_ws;
    size_t off = 0;
    auto alloc = [&](size_t bytes) -> char* {
        char* p = ws + off;
        off += (bytes + 255) & ~(size_t)255;
        return p;
    };
    int*      offs   = (int*)alloc((size_t)(N + 1) * 4);
    int*      adj    = (int*)alloc((size_t)E * 4);
    int*      cnt    = (int*)alloc((size_t)NBA * NBUCK * 4);
    int*      basep  = (int*)alloc((size_t)NBA * NBUCK * 4);
    int*      boff   = (int*)alloc((size_t)(NBUCK + 1) * 4);
    float*    b0     = (float*)alloc((size_t)N * DD * 4);
    float*    b1     = (float*)alloc((size_t)N * DD * 4);
    float*    aggbuf = (float*)alloc((size_t)N * DD * 4);
    unsigned* Bp     = (unsigned*)alloc((size_t)L * 2 * 16 * 64 * 4 * 4);
    float*    sumsA  = (float*)alloc((size_t)G * DD * 4);
    float*    sumsX  = (float*)alloc((size_t)G * DD * 4);
    const size_t bfbytes = (size_t)N * DD * 2;
    unsigned short* bfA = (unsigned short*)alloc(bfbytes);
    unsigned short* bfB = (unsigned short*)alloc(bfbytes);
    const bool use_bf16 = (off <= ws_size);

    // ebuf aliases b0 (dead until first mfma_gemm, stream-ordered after sort):
    // E*4 = 4MB <= N*DD*4 = 25.6MB.
    unsigned* ebuf = (unsigned*)b0;

    // ---- CSR build: all-coalesced counting sort ----
    const size_t ldsN = (size_t)NBUCK * 4;
    bucket_count<<<NBA, 256, ldsN, stream>>>(dst, cnt, E, NBUCK);
    bucket_base<<<1, 1024, 0, stream>>>(cnt, basep, boff, offs, NBUCK, E, N);
    bucket_scatter<<<NBA, 256, ldsN, stream>>>(src, dst, basep, ebuf, E, NBUCK);
    bucket_sort<<<NBUCK, 256, 0, stream>>>(ebuf, boff, offs, adj, N);

    // ---- pack W into MFMA fragment layout (all layers) ----
    pack_B<<<(L * 16 * 64 + 255) / 256, 256, 0, stream>>>(Wl, Wr, Bp, L);

    // ---- layers 0..L-2: aggregate + MFMA gemm (ping-pong) ----
    const float* cur = x;
    float* bufs[2] = {b0, b1};
    unsigned short* bfs[2] = {bfB, bfA};   // gemm layer l writes bfs[l&1]
    const unsigned short* curb = bfA;      // bf16 view of cur

    if (use_bf16) {
        const long long n8 = (long long)N * DD / 8;
        cast_bf16<<<(int)((n8 + 255) / 256), 256, 0, stream>>>(x, bfA, n8);
    }

    const int aggB_blocks = (N * 8 + 255) / 256;
    const int aggF_blocks = (N * 16 + 255) / 256;
    for (int l = 0; l < L - 1; ++l) {
        float* outb = bufs[l & 1];
        if (use_bf16) {
            aggregate_bf16<<<aggB_blocks, 256, 0, stream>>>(curb, aggbuf, offs, adj, N);
        } else {
            aggregate<<<aggF_blocks, 256, 0, stream>>>(cur, aggbuf, offs, adj, N);
        }
        mfma_gemm<<<1024, 256, 0, stream>>>(aggbuf, cur, outb,
                                            use_bf16 ? bfs[l & 1] : (unsigned short*)nullptr,
                                            Bp + (size_t)l * 2 * 16 * 64 * 4,
                                            bl + (size_t)l * DD, N);
        cur = outb;
        curb = bfs[l & 1];
    }

    // ---- last layer: pooling is linear -> pool(agg), pool(x), tiny GEMM ----
    if (use_bf16) {
        aggregate_bf16<<<aggB_blocks, 256, 0, stream>>>(curb, aggbuf, offs, adj, N);
    } else {
        aggregate<<<aggF_blocks, 256, 0, stream>>>(cur, aggbuf, offs, adj, N);
    }
    hipMemsetAsync(sumsA, 0, (size_t)G * DD * 4, stream);
    hipMemsetAsync(sumsX, 0, (size_t)G * DD * 4, stream);
    pool_partial2<<<2048, 256, 0, stream>>>(aggbuf, cur, batch, sumsA, sumsX, N);
    final_gemm<<<G, DD, 0, stream>>>(sumsA, sumsX, batch,
                                     Wl + (size_t)(L - 1) * DD * DD,
                                     bl + (size_t)(L - 1) * DD,
                                     Wr + (size_t)(L - 1) * DD * DD,
                                     (float*)d_out, N);
}

// Round 11
// 196.222 us; speedup vs baseline: 2.4212x; 1.1773x over previous
//
#include <hip/hip_runtime.h>

// GraphSAGE (mean) x3 + per-graph mean pool, MI355X.
// R11: bucket_base (single-block, serial 128-deep per-thread scan, 41-61us at
// 0.09% occupancy) split into (a) bucket_prescan: one WAVE per bucket,
// shfl_up scan over the 128 per-block counts -- all loads in flight at once;
// (b) bucket_toff: single-block scan over just the 391 bucket totals.
// bucket_scatter folds boff[k] at pos-init. CSR write path (R10's coalesced
// counting sort) unchanged.

#define DD 64
#define NBA 128    // blocks in count/scatter passes (= 2 x wave width)
#define CAP 4096   // per-bucket LDS sort capacity (avg bucket ~2560 edges)

typedef __attribute__((ext_vector_type(8))) short short8;   // 8 bf16 (4 VGPRs)
typedef __attribute__((ext_vector_type(4))) float f32x4;    // MFMA accumulator

__device__ inline short8 pack4(unsigned a, unsigned b, unsigned c, unsigned d) {
    union { uint4 u; short8 s; } un;
    un.u = make_uint4(a, b, c, d);
    return un.s;
}

__device__ inline unsigned rne_bf16(float v) {   // round-to-nearest-even, high16
    unsigned u = __float_as_uint(v);
    return (u + 0x7FFFu + ((u >> 16) & 1u)) >> 16;
}

// ---------------- CSR 1: per-block bucket histogram (LDS, coalesced out) ----
__global__ __launch_bounds__(256) void bucket_count(
    const int* __restrict__ dst, int* __restrict__ cnt, int E, int NBUCK) {
    extern __shared__ int hist[];   // NBUCK ints
    const int b = blockIdx.x;
    const int per = (E + NBA - 1) / NBA;
    const int lo = b * per, hi = min(lo + per, E);
    for (int k = threadIdx.x; k < NBUCK; k += 256) hist[k] = 0;
    __syncthreads();
    for (int e = lo + threadIdx.x; e < hi; e += 256)
        atomicAdd(&hist[dst[e] >> 8], 1);
    __syncthreads();
    for (int k = threadIdx.x; k < NBUCK; k += 256)
        cnt[b * NBUCK + k] = hist[k];
}

// ---------------- CSR 2a: per-bucket scan over the NBA=128 block counts -----
// One wave per bucket. lane b and b+64 hold cnt[b][k]; shfl_up inclusive scan
// gives block-local exclusive bases; lane 63 emits the bucket total.
__global__ __launch_bounds__(256) void bucket_prescan(
    const int* __restrict__ cnt, int* __restrict__ base,
    int* __restrict__ tot, int NBUCK) {
    const int lane = threadIdx.x & 63;
    const int k = (int)((blockIdx.x * 256 + threadIdx.x) >> 6);
    if (k >= NBUCK) return;
    int v0 = cnt[(size_t)lane * NBUCK + k];
    int v1 = cnt[(size_t)(lane + 64) * NBUCK + k];
    int s0 = v0, s1 = v1;
#pragma unroll
    for (int o = 1; o < 64; o <<= 1) {
        const int u0 = __shfl_up(s0, o, 64);
        const int u1 = __shfl_up(s1, o, 64);
        if (lane >= o) { s0 += u0; s1 += u1; }
    }
    const int total0 = __shfl(s0, 63, 64);
    base[(size_t)lane * NBUCK + k] = s0 - v0;                 // exclusive
    base[(size_t)(lane + 64) * NBUCK + k] = total0 + s1 - v1;
    if (lane == 63) tot[k] = total0 + s1;
}

// ---------------- CSR 2b: exclusive scan over NBUCK bucket totals -----------
__global__ __launch_bounds__(1024) void bucket_toff(
    const int* __restrict__ tot, int* __restrict__ boff,
    int* __restrict__ offs, int NBUCK, int E, int N) {
    __shared__ int s[1024];
    __shared__ int carry_s;
    const int t = threadIdx.x;
    if (t == 0) carry_s = 0;
    __syncthreads();
    for (int cs = 0; cs < NBUCK; cs += 1024) {
        const int i = cs + t;
        const int v = (i < NBUCK) ? tot[i] : 0;
        s[t] = v;
        __syncthreads();
        for (int o = 1; o < 1024; o <<= 1) {
            const int a = (t >= o) ? s[t - o] : 0;
            __syncthreads();
            s[t] += a;
            __syncthreads();
        }
        const int carry = carry_s;
        if (i < NBUCK) boff[i] = carry + s[t] - v;
        __syncthreads();
        if (t == 1023) carry_s = carry + s[1023];
        __syncthreads();
    }
    if (t == 0) { boff[NBUCK] = E; offs[N] = E; }
}

// ---------------- CSR 3: packed scatter into block-private runs -------------
__global__ __launch_bounds__(256) void bucket_scatter(
    const int* __restrict__ src, const int* __restrict__ dst,
    const int* __restrict__ base, const int* __restrict__ boff,
    unsigned* __restrict__ ebuf, int E, int NBUCK) {
    extern __shared__ int pos[];   // NBUCK ints
    const int b = blockIdx.x;
    const int per = (E + NBA - 1) / NBA;
    const int lo = b * per, hi = min(lo + per, E);
    for (int k = threadIdx.x; k < NBUCK; k += 256)
        pos[k] = base[b * NBUCK + k] + boff[k];
    __syncthreads();
    for (int e = lo + threadIdx.x; e < hi; e += 256) {
        const int d = dst[e];
        const int s = src[e];
        const int p = atomicAdd(&pos[d >> 8], 1);          // LDS only
        ebuf[p] = ((unsigned)(d & 255) << 24) | (unsigned)s;
    }
}

// ---------------- CSR 4: per-bucket LDS counting sort -----------------------
__global__ __launch_bounds__(256) void bucket_sort(
    const unsigned* __restrict__ ebuf, const int* __restrict__ boff,
    int* __restrict__ offs, int* __restrict__ adj, int N) {
    const int b  = blockIdx.x;
    const int lo = boff[b];
    const int sz = boff[b + 1] - lo;
    const int base = b << 8;
    const int t = threadIdx.x;

    __shared__ int hist[256];
    __shared__ int hcur[256];
    __shared__ unsigned sbuf[CAP];

    hist[t] = 0;
    __syncthreads();
    for (int i = t; i < sz; i += 256)
        atomicAdd(&hist[ebuf[lo + i] >> 24], 1);
    __syncthreads();
    int v = hist[t];
    hcur[t] = v;
    __syncthreads();
    for (int o = 1; o < 256; o <<= 1) {
        const int a = (t >= o) ? hcur[t - o] : 0;
        __syncthreads();
        hcur[t] += a;
        __syncthreads();
    }
    const int ex = hcur[t] - v;
    __syncthreads();
    hcur[t] = ex;
    if (base + t < N) offs[base + t] = lo + ex;
    __syncthreads();

    if (sz <= CAP) {
        for (int i = t; i < sz; i += 256) {
            const unsigned w = ebuf[lo + i];
            const int p = atomicAdd(&hcur[w >> 24], 1);
            sbuf[p] = w & 0x00FFFFFFu;
        }
        __syncthreads();
        for (int i = t; i < sz; i += 256) adj[lo + i] = (int)sbuf[i];   // coalesced
    } else {                          // skew fallback (correct, uncoalesced)
        for (int i = t; i < sz; i += 256) {
            const unsigned w = ebuf[lo + i];
            const int p = atomicAdd(&hcur[w >> 24], 1);
            adj[lo + p] = (int)(w & 0x00FFFFFFu);
        }
    }
}

// ---------------- fp32 -> bf16 (RNE) cast, 8 elems/thread ----------------
__global__ __launch_bounds__(256) void cast_bf16(
    const float* __restrict__ in, unsigned short* __restrict__ outb, long long n8) {
    const long long t = (long long)blockIdx.x * 256 + threadIdx.x;
    if (t >= n8) return;
    const float4 v0 = *reinterpret_cast<const float4*>(in + t * 8);
    const float4 v1 = *reinterpret_cast<const float4*>(in + t * 8 + 4);
    uint4 o;
    o.x = rne_bf16(v0.x) | (rne_bf16(v0.y) << 16);
    o.y = rne_bf16(v0.z) | (rne_bf16(v0.w) << 16);
    o.z = rne_bf16(v1.x) | (rne_bf16(v1.y) << 16);
    o.w = rne_bf16(v1.z) | (rne_bf16(v1.w) << 16);
    *reinterpret_cast<uint4*>(outb + t * 8) = o;
}

// ---------------- gather-mean from bf16 rows (8 threads/node) --------------
__global__ __launch_bounds__(256) void aggregate_bf16(
    const unsigned short* __restrict__ xb, float* __restrict__ agg,
    const int* __restrict__ offs, const int* __restrict__ adj, int n) {
    const int t  = blockIdx.x * 256 + threadIdx.x;
    const int nd = t >> 3;
    const int c8 = (t & 7) * 8;
    if (nd >= n) return;

    const int s = offs[nd];
    const int e = offs[nd + 1];

    float a0[8], a1[8], a2[8], a3[8];
#pragma unroll
    for (int p = 0; p < 8; ++p) { a0[p] = 0.f; a1[p] = 0.f; a2[p] = 0.f; a3[p] = 0.f; }

#define ACC8(A, U)                                                             \
    do {                                                                       \
        A[0] += __uint_as_float((U).x << 16);                                  \
        A[1] += __uint_as_float((U).x & 0xFFFF0000u);                          \
        A[2] += __uint_as_float((U).y << 16);                                  \
        A[3] += __uint_as_float((U).y & 0xFFFF0000u);                          \
        A[4] += __uint_as_float((U).z << 16);                                  \
        A[5] += __uint_as_float((U).z & 0xFFFF0000u);                          \
        A[6] += __uint_as_float((U).w << 16);                                  \
        A[7] += __uint_as_float((U).w & 0xFFFF0000u);                          \
    } while (0)

    int j = s;
    for (; j + 4 <= e; j += 4) {
        const int i0 = adj[j], i1 = adj[j + 1], i2 = adj[j + 2], i3 = adj[j + 3];
        const uint4 u0 = *reinterpret_cast<const uint4*>(xb + (size_t)i0 * DD + c8);
        const uint4 u1 = *reinterpret_cast<const uint4*>(xb + (size_t)i1 * DD + c8);
        const uint4 u2 = *reinterpret_cast<const uint4*>(xb + (size_t)i2 * DD + c8);
        const uint4 u3 = *reinterpret_cast<const uint4*>(xb + (size_t)i3 * DD + c8);
        ACC8(a0, u0); ACC8(a1, u1); ACC8(a2, u2); ACC8(a3, u3);
    }
    for (; j < e; ++j) {
        const uint4 u = *reinterpret_cast<const uint4*>(xb + (size_t)adj[j] * DD + c8);
        ACC8(a0, u);
    }
#undef ACC8

    const int deg = e - s;
    const float inv = (deg > 0) ? (1.0f / (float)deg) : 1.0f;
    float4 r0, r1;
    r0.x = (a0[0] + a1[0] + a2[0] + a3[0]) * inv;
    r0.y = (a0[1] + a1[1] + a2[1] + a3[1]) * inv;
    r0.z = (a0[2] + a1[2] + a2[2] + a3[2]) * inv;
    r0.w = (a0[3] + a1[3] + a2[3] + a3[3]) * inv;
    r1.x = (a0[4] + a1[4] + a2[4] + a3[4]) * inv;
    r1.y = (a0[5] + a1[5] + a2[5] + a3[5]) * inv;
    r1.z = (a0[6] + a1[6] + a2[6] + a3[6]) * inv;
    r1.w = (a0[7] + a1[7] + a2[7] + a3[7]) * inv;
    *reinterpret_cast<float4*>(agg + (size_t)nd * DD + c8)     = r0;
    *reinterpret_cast<float4*>(agg + (size_t)nd * DD + c8 + 4) = r1;
}

// ---------------- fp32 gather fallback (16 threads/node) ----------------
__global__ __launch_bounds__(256) void aggregate(
    const float* __restrict__ xin, float* __restrict__ agg,
    const int* __restrict__ offs, const int* __restrict__ adj, int n) {
    const int t  = blockIdx.x * 256 + threadIdx.x;
    const int nd = t >> 4;
    const int c  = (t & 15) * 4;
    if (nd >= n) return;
    const int s = offs[nd];
    const int e = offs[nd + 1];
    float4 a0 = {0.f, 0.f, 0.f, 0.f};
    float4 a1 = {0.f, 0.f, 0.f, 0.f};
    float4 a2 = {0.f, 0.f, 0.f, 0.f};
    float4 a3 = {0.f, 0.f, 0.f, 0.f};
    int j = s;
    for (; j + 4 <= e; j += 4) {
        const int i0 = adj[j], i1 = adj[j + 1], i2 = adj[j + 2], i3 = adj[j + 3];
        const float4 v0 = *reinterpret_cast<const float4*>(xin + (size_t)i0 * DD + c);
        const float4 v1 = *reinterpret_cast<const float4*>(xin + (size_t)i1 * DD + c);
        const float4 v2 = *reinterpret_cast<const float4*>(xin + (size_t)i2 * DD + c);
        const float4 v3 = *reinterpret_cast<const float4*>(xin + (size_t)i3 * DD + c);
        a0.x += v0.x; a0.y += v0.y; a0.z += v0.z; a0.w += v0.w;
        a1.x += v1.x; a1.y += v1.y; a1.z += v1.z; a1.w += v1.w;
        a2.x += v2.x; a2.y += v2.y; a2.z += v2.z; a2.w += v2.w;
        a3.x += v3.x; a3.y += v3.y; a3.z += v3.z; a3.w += v3.w;
    }
    for (; j < e; ++j) {
        const float4 v = *reinterpret_cast<const float4*>(xin + (size_t)adj[j] * DD + c);
        a0.x += v.x; a0.y += v.y; a0.z += v.z; a0.w += v.w;
    }
    const int deg = e - s;
    const float inv = (deg > 0) ? (1.0f / (float)deg) : 1.0f;
    float4 r;
    r.x = (a0.x + a1.x + a2.x + a3.x) * inv;
    r.y = (a0.y + a1.y + a2.y + a3.y) * inv;
    r.z = (a0.z + a1.z + a2.z + a3.z) * inv;
    r.w = (a0.w + a1.w + a2.w + a3.w) * inv;
    *reinterpret_cast<float4*>(agg + (size_t)nd * DD + c) = r;
}

// ---------------- W pre-pack into MFMA B-fragment layout, bf16 hi/lo --------
__global__ void pack_B(const float* __restrict__ Wl, const float* __restrict__ Wr,
                       unsigned* __restrict__ Bp, int L) {
    int t = blockIdx.x * 256 + threadIdx.x;
    int wv = t >> 6, lane = t & 63;
    if (wv >= L * 16) return;
    int layer = wv >> 4;
    int fid = wv & 15;
    int ks = fid >> 2, nt = fid & 3;
    int j = nt * 16 + (lane & 15);
    int kb = ks * 32 + (lane >> 4) * 8;
    const float* wl = Wl + (size_t)layer * DD * DD;
    const float* wr = Wr + (size_t)layer * DD * DD;
    unsigned hi[8], lo[8];
#pragma unroll
    for (int s = 0; s < 8; ++s) {
        int k = kb + s;
        float v = (k < DD) ? wl[k * DD + j] : wr[(k - DD) * DD + j];
        unsigned u = __float_as_uint(v);
        unsigned h = u & 0xFFFF0000u;
        hi[s] = h;
        float lf = v - __uint_as_float(h);         // exact residual
        lo[s] = __float_as_uint(lf) & 0xFFFF0000u;
    }
    size_t base_hi = ((size_t)(layer * 2 + 0) * 16 + fid) * 64 + lane;
    size_t base_lo = ((size_t)(layer * 2 + 1) * 16 + fid) * 64 + lane;
#pragma unroll
    for (int p = 0; p < 4; ++p) {
        Bp[base_hi * 4 + p] = (hi[2 * p] >> 16) | hi[2 * p + 1];
        Bp[base_lo * 4 + p] = (lo[2 * p] >> 16) | lo[2 * p + 1];
    }
}

// ---------------- layer GEMM + optional bf16 copy of the output -------------
__global__ __launch_bounds__(256, 2) void mfma_gemm(
    const float* __restrict__ g, const float* __restrict__ x,
    float* __restrict__ out, unsigned short* __restrict__ outb,   // may be null
    const unsigned* __restrict__ Bp, const float* __restrict__ bias, int n) {
    const int lane = threadIdx.x & 63;
    const int wv   = (int)((blockIdx.x * 256 + threadIdx.x) >> 6);
    const int nwv  = (int)((gridDim.x * 256) >> 6);

    short8 Bh[4][4], Bl[4][4];
#pragma unroll
    for (int ks = 0; ks < 4; ++ks)
#pragma unroll
        for (int nt = 0; nt < 4; ++nt) {
            int fid = ks * 4 + nt;
            const uint4 h = *reinterpret_cast<const uint4*>(Bp + ((size_t)fid * 64 + lane) * 4);
            const uint4 l = *reinterpret_cast<const uint4*>(Bp + ((size_t)(16 + fid) * 64 + lane) * 4);
            Bh[ks][nt] = pack4(h.x, h.y, h.z, h.w);
            Bl[ks][nt] = pack4(l.x, l.y, l.z, l.w);
        }

    float bv[4];
#pragma unroll
    for (int nt = 0; nt < 4; ++nt) bv[nt] = bias[nt * 16 + (lane & 15)];

    const int ntiles = (n + 15) >> 4;
    for (int tile = wv; tile < ntiles; tile += nwv) {
        const int row = tile * 16 + (lane & 15);
        const bool ok = row < n;
        const float* grow = g + (size_t)row * DD + (lane >> 4) * 8;
        const float* xrow = x + (size_t)row * DD + (lane >> 4) * 8;

        f32x4 acc[4];
#pragma unroll
        for (int nt = 0; nt < 4; ++nt) acc[nt] = (f32x4){bv[nt], bv[nt], bv[nt], bv[nt]};

#pragma unroll
        for (int ks = 0; ks < 4; ++ks) {
            const float* base = ((ks < 2) ? grow : xrow) + (ks & 1) * 32;
            f32x4 v0 = ok ? *reinterpret_cast<const f32x4*>(base)
                          : (f32x4){0.f, 0.f, 0.f, 0.f};
            f32x4 v1 = ok ? *reinterpret_cast<const f32x4*>(base + 4)
                          : (f32x4){0.f, 0.f, 0.f, 0.f};
            float vv[8] = {v0[0], v0[1], v0[2], v0[3], v1[0], v1[1], v1[2], v1[3]};
            unsigned hu[4], lu[4];
#pragma unroll
            for (int p = 0; p < 4; ++p) {
                unsigned ua = __float_as_uint(vv[2 * p]);
                unsigned ub = __float_as_uint(vv[2 * p + 1]);
                unsigned ha = ua & 0xFFFF0000u, hb = ub & 0xFFFF0000u;
                hu[p] = (ha >> 16) | hb;
                float la = vv[2 * p]     - __uint_as_float(ha);
                float lb = vv[2 * p + 1] - __uint_as_float(hb);
                lu[p] = ((__float_as_uint(la) & 0xFFFF0000u) >> 16) |
                        (__float_as_uint(lb) & 0xFFFF0000u);
            }
            const short8 Ah = pack4(hu[0], hu[1], hu[2], hu[3]);
            const short8 Al = pack4(lu[0], lu[1], lu[2], lu[3]);
#pragma unroll
            for (int nt = 0; nt < 4; ++nt) {
                acc[nt] = __builtin_amdgcn_mfma_f32_16x16x32_bf16(Ah, Bh[ks][nt], acc[nt], 0, 0, 0);
                acc[nt] = __builtin_amdgcn_mfma_f32_16x16x32_bf16(Al, Bh[ks][nt], acc[nt], 0, 0, 0);
                acc[nt] = __builtin_amdgcn_mfma_f32_16x16x32_bf16(Ah, Bl[ks][nt], acc[nt], 0, 0, 0);
            }
        }

        // C/D layout (verified): col = lane&15, row = (lane>>4)*4 + reg
        const int r0 = tile * 16 + (lane >> 4) * 4;
#pragma unroll
        for (int r = 0; r < 4; ++r) {
            const int rr = r0 + r;
            if (rr < n) {
#pragma unroll
                for (int nt = 0; nt < 4; ++nt) {
                    const float v = acc[nt][r];
                    const size_t idx = (size_t)rr * DD + nt * 16 + (lane & 15);
                    out[idx] = v;
                    if (outb) outb[idx] = (unsigned short)rne_bf16(v);
                }
            }
        }
    }
}

// ---------------- pooling partials over TWO arrays at once ----------------
__global__ __launch_bounds__(256) void pool_partial2(
    const float* __restrict__ xa, const float* __restrict__ xb,
    const int* __restrict__ batch,
    float* __restrict__ sumsA, float* __restrict__ sumsB, int n) {
    const int lane = threadIdx.x & 63;
    const int wv   = (int)((blockIdx.x * blockDim.x + threadIdx.x) >> 6);
    const int nwv  = (int)((gridDim.x * blockDim.x) >> 6);
    const int chunk = (n + nwv - 1) / nwv;
    const int start = wv * chunk;
    if (start >= n) return;
    const int end = min(start + chunk, n);

    int g = batch[start];
    float accA = 0.f, accB = 0.f;
    for (int nd = start; nd < end; ++nd) {
        const int bg = batch[nd];
        if (bg != g) {
            atomicAdd(&sumsA[(size_t)g * DD + lane], accA);
            atomicAdd(&sumsB[(size_t)g * DD + lane], accB);
            accA = 0.f; accB = 0.f;
            g = bg;
        }
        accA += xa[(size_t)nd * DD + lane];
        accB += xb[(size_t)nd * DD + lane];
    }
    atomicAdd(&sumsA[(size_t)g * DD + lane], accA);
    atomicAdd(&sumsB[(size_t)g * DD + lane], accB);
}

// ---------------- final: out[g] = mean(agg3)@Wl + mean(x2)@Wr + b ----------
__global__ void final_gemm(const float* __restrict__ sumsA, const float* __restrict__ sumsX,
                           const int* __restrict__ batch,
                           const float* __restrict__ Wl, const float* __restrict__ bl,
                           const float* __restrict__ Wr,
                           float* __restrict__ out, int n) {
    const int g = blockIdx.x;
    const int d = threadIdx.x;  // 64 threads

    int lo = 0, hi = n;
    while (lo < hi) { int m = (lo + hi) >> 1; if (batch[m] < g) lo = m + 1; else hi = m; }
    const int st = lo;
    lo = 0; hi = n;
    while (lo < hi) { int m = (lo + hi) >> 1; if (batch[m] < g + 1) lo = m + 1; else hi = m; }
    const int c = lo - st;

    if (c == 0) {                    // reference: empty graph -> 0 (not bias)
        out[(size_t)g * DD + d] = 0.f;
        return;
    }
    const float inv = 1.0f / (float)c;

    __shared__ float sa[DD], sx[DD];
    sa[d] = sumsA[(size_t)g * DD + d] * inv;
    sx[d] = sumsX[(size_t)g * DD + d] * inv;
    __syncthreads();

    float acc = bl[d];
#pragma unroll 8
    for (int k = 0; k < DD; ++k) acc += sa[k] * Wl[k * DD + d];
#pragma unroll 8
    for (int k = 0; k < DD; ++k) acc += sx[k] * Wr[k * DD + d];
    out[(size_t)g * DD + d] = acc;
}

extern "C" void kernel_launch(void* const* d_in, const int* in_sizes, int n_in,
                              void* d_out, int out_size, void* d_ws, size_t ws_size,
                              hipStream_t stream) {
    const float* x     = (const float*)d_in[0];
    const int*   ei    = (const int*)d_in[1];
    const int*   batch = (const int*)d_in[2];
    const float* Wl    = (const float*)d_in[3];
    const float* bl    = (const float*)d_in[4];
    const float* Wr    = (const float*)d_in[5];

    const int N = in_sizes[0] / DD;
    const int E = in_sizes[1] / 2;
    const int L = in_sizes[3] / (DD * DD);
    const int G = out_size / DD;
    const int NBUCK = (N + 255) >> 8;          // 256-node buckets

    const int* src = ei;        // edge_index[0]
    const int* dst = ei + E;    // edge_index[1]

    char* ws = (char*)d_ws;
    size_t off = 0;
    auto alloc = [&](size_t bytes) -> char* {
        char* p = ws + off;
        off += (bytes + 255) & ~(size_t)255;
        return p;
    };
    int*      offs   = (int*)alloc((size_t)(N + 1) * 4);
    int*      adj    = (int*)alloc((size_t)E * 4);
    int*      cnt    = (int*)alloc((size_t)NBA * NBUCK * 4);
    int*      basep  = (int*)alloc((size_t)NBA * NBUCK * 4);
    int*      boff   = (int*)alloc((size_t)(NBUCK + 1) * 4);
    int*      tot    = (int*)alloc((size_t)NBUCK * 4);
    float*    b0     = (float*)alloc((size_t)N * DD * 4);
    float*    b1     = (float*)alloc((size_t)N * DD * 4);
    float*    aggbuf = (float*)alloc((size_t)N * DD * 4);
    unsigned* Bp     = (unsigned*)alloc((size_t)L * 2 * 16 * 64 * 4 * 4);
    float*    sumsA  = (float*)alloc((size_t)G * DD * 4);
    float*    sumsX  = (float*)alloc((size_t)G * DD * 4);
    const size_t bfbytes = (size_t)N * DD * 2;
    unsigned short* bfA = (unsigned short*)alloc(bfbytes);
    unsigned short* bfB = (unsigned short*)alloc(bfbytes);
    const bool use_bf16 = (off <= ws_size);

    // ebuf aliases b0 (dead until first mfma_gemm, stream-ordered after sort)
    unsigned* ebuf = (unsigned*)b0;

    // ---- CSR build: all-coalesced counting sort, parallel prefix passes ----
    const size_t ldsN = (size_t)NBUCK * 4;
    bucket_count<<<NBA, 256, ldsN, stream>>>(dst, cnt, E, NBUCK);
    bucket_prescan<<<(NBUCK * 64 + 255) / 256, 256, 0, stream>>>(cnt, basep, tot, NBUCK);
    bucket_toff<<<1, 1024, 0, stream>>>(tot, boff, offs, NBUCK, E, N);
    bucket_scatter<<<NBA, 256, ldsN, stream>>>(src, dst, basep, boff, ebuf, E, NBUCK);
    bucket_sort<<<NBUCK, 256, 0, stream>>>(ebuf, boff, offs, adj, N);

    // ---- pack W into MFMA fragment layout (all layers) ----
    pack_B<<<(L * 16 * 64 + 255) / 256, 256, 0, stream>>>(Wl, Wr, Bp, L);

    // ---- layers 0..L-2: aggregate + MFMA gemm (ping-pong) ----
    const float* cur = x;
    float* bufs[2] = {b0, b1};
    unsigned short* bfs[2] = {bfB, bfA};   // gemm layer l writes bfs[l&1]
    const unsigned short* curb = bfA;      // bf16 view of cur

    if (use_bf16) {
        const long long n8 = (long long)N * DD / 8;
        cast_bf16<<<(int)((n8 + 255) / 256), 256, 0, stream>>>(x, bfA, n8);
    }

    const int aggB_blocks = (N * 8 + 255) / 256;
    const int aggF_blocks = (N * 16 + 255) / 256;
    for (int l = 0; l < L - 1; ++l) {
        float* outb = bufs[l & 1];
        if (use_bf16) {
            aggregate_bf16<<<aggB_blocks, 256, 0, stream>>>(curb, aggbuf, offs, adj, N);
        } else {
            aggregate<<<aggF_blocks, 256, 0, stream>>>(cur, aggbuf, offs, adj, N);
        }
        mfma_gemm<<<1024, 256, 0, stream>>>(aggbuf, cur, outb,
                                            use_bf16 ? bfs[l & 1] : (unsigned short*)nullptr,
                                            Bp + (size_t)l * 2 * 16 * 64 * 4,
                                            bl + (size_t)l * DD, N);
        cur = outb;
        curb = bfs[l & 1];
    }

    // ---- last layer: pooling is linear -> pool(agg), pool(x), tiny GEMM ----
    if (use_bf16) {
        aggregate_bf16<<<aggB_blocks, 256, 0, stream>>>(curb, aggbuf, offs, adj, N);
    } else {
        aggregate<<<aggF_blocks, 256, 0, stream>>>(cur, aggbuf, offs, adj, N);
    }
    hipMemsetAsync(sumsA, 0, (size_t)G * DD * 4, stream);
    hipMemsetAsync(sumsX, 0, (size_t)G * DD * 4, stream);
    pool_partial2<<<2048, 256, 0, stream>>>(aggbuf, cur, batch, sumsA, sumsX, N);
    final_gemm<<<G, DD, 0, stream>>>(sumsA, sumsX, batch,
                                     Wl + (size_t)(L - 1) * DD * DD,
                                     bl + (size_t)(L - 1) * DD,
                                     Wr + (size_t)(L - 1) * DD * DD,
                                     (float*)d_out, N);
}

// Round 12
// 185.106 us; speedup vs baseline: 2.5666x; 1.0600x over previous
//
#include <hip/hip_runtime.h>

// GraphSAGE (mean) x3 + per-graph mean pool, MI355X.
// R12: all-bf16 inter-layer activations. The fp32 layer-output stream was
// only feeding the next gemm's x-operand; bf16 is enough (gather path already
// bf16, absmax headroom 5x). gemm: x-side A-frag = loaded uint4 directly
// (2 MFMAs: Ah*Bh + Ah*Bl); agg-side keeps exact fp32 hi/lo split (3 MFMAs).
// Deletes 25.6MB fp32 write + 25.6MB fp32 read per gemm, and b0/b1 buffers.

#define DD 64
#define NBA 128    // blocks in count/scatter passes (= 2 x wave width)
#define CAP 4096   // per-bucket LDS sort capacity (avg bucket ~2560 edges)

typedef __attribute__((ext_vector_type(8))) short short8;   // 8 bf16 (4 VGPRs)
typedef __attribute__((ext_vector_type(4))) float f32x4;    // MFMA accumulator

__device__ inline short8 pack4(unsigned a, unsigned b, unsigned c, unsigned d) {
    union { uint4 u; short8 s; } un;
    un.u = make_uint4(a, b, c, d);
    return un.s;
}

__device__ inline short8 as_short8(uint4 u) {
    union { uint4 u4; short8 s; } un;
    un.u4 = u;
    return un.s;
}

__device__ inline unsigned rne_bf16(float v) {   // round-to-nearest-even, high16
    unsigned u = __float_as_uint(v);
    return (u + 0x7FFFu + ((u >> 16) & 1u)) >> 16;
}

// ---------------- CSR 1: per-block bucket histogram ----------------
__global__ __launch_bounds__(256) void bucket_count(
    const int* __restrict__ dst, int* __restrict__ cnt, int E, int NBUCK) {
    extern __shared__ int hist[];   // NBUCK ints
    const int b = blockIdx.x;
    const int per = (E + NBA - 1) / NBA;
    const int lo = b * per, hi = min(lo + per, E);
    for (int k = threadIdx.x; k < NBUCK; k += 256) hist[k] = 0;
    __syncthreads();
    for (int e = lo + threadIdx.x; e < hi; e += 256)
        atomicAdd(&hist[dst[e] >> 8], 1);
    __syncthreads();
    for (int k = threadIdx.x; k < NBUCK; k += 256)
        cnt[b * NBUCK + k] = hist[k];
}

// ---------------- CSR 2a: per-bucket wave scan over 128 block counts --------
__global__ __launch_bounds__(256) void bucket_prescan(
    const int* __restrict__ cnt, int* __restrict__ base,
    int* __restrict__ tot, int NBUCK) {
    const int lane = threadIdx.x & 63;
    const int k = (int)((blockIdx.x * 256 + threadIdx.x) >> 6);
    if (k >= NBUCK) return;
    int v0 = cnt[(size_t)lane * NBUCK + k];
    int v1 = cnt[(size_t)(lane + 64) * NBUCK + k];
    int s0 = v0, s1 = v1;
#pragma unroll
    for (int o = 1; o < 64; o <<= 1) {
        const int u0 = __shfl_up(s0, o, 64);
        const int u1 = __shfl_up(s1, o, 64);
        if (lane >= o) { s0 += u0; s1 += u1; }
    }
    const int total0 = __shfl(s0, 63, 64);
    base[(size_t)lane * NBUCK + k] = s0 - v0;                 // exclusive
    base[(size_t)(lane + 64) * NBUCK + k] = total0 + s1 - v1;
    if (lane == 63) tot[k] = total0 + s1;
}

// ---------------- CSR 2b: exclusive scan over NBUCK bucket totals -----------
__global__ __launch_bounds__(1024) void bucket_toff(
    const int* __restrict__ tot, int* __restrict__ boff,
    int* __restrict__ offs, int NBUCK, int E, int N) {
    __shared__ int s[1024];
    __shared__ int carry_s;
    const int t = threadIdx.x;
    if (t == 0) carry_s = 0;
    __syncthreads();
    for (int cs = 0; cs < NBUCK; cs += 1024) {
        const int i = cs + t;
        const int v = (i < NBUCK) ? tot[i] : 0;
        s[t] = v;
        __syncthreads();
        for (int o = 1; o < 1024; o <<= 1) {
            const int a = (t >= o) ? s[t - o] : 0;
            __syncthreads();
            s[t] += a;
            __syncthreads();
        }
        const int carry = carry_s;
        if (i < NBUCK) boff[i] = carry + s[t] - v;
        __syncthreads();
        if (t == 1023) carry_s = carry + s[1023];
        __syncthreads();
    }
    if (t == 0) { boff[NBUCK] = E; offs[N] = E; }
}

// ---------------- CSR 3: packed scatter into block-private runs -------------
__global__ __launch_bounds__(256) void bucket_scatter(
    const int* __restrict__ src, const int* __restrict__ dst,
    const int* __restrict__ base, const int* __restrict__ boff,
    unsigned* __restrict__ ebuf, int E, int NBUCK) {
    extern __shared__ int pos[];   // NBUCK ints
    const int b = blockIdx.x;
    const int per = (E + NBA - 1) / NBA;
    const int lo = b * per, hi = min(lo + per, E);
    for (int k = threadIdx.x; k < NBUCK; k += 256)
        pos[k] = base[b * NBUCK + k] + boff[k];
    __syncthreads();
    for (int e = lo + threadIdx.x; e < hi; e += 256) {
        const int d = dst[e];
        const int s = src[e];
        const int p = atomicAdd(&pos[d >> 8], 1);          // LDS only
        ebuf[p] = ((unsigned)(d & 255) << 24) | (unsigned)s;
    }
}

// ---------------- CSR 4: per-bucket LDS counting sort -----------------------
__global__ __launch_bounds__(256) void bucket_sort(
    const unsigned* __restrict__ ebuf, const int* __restrict__ boff,
    int* __restrict__ offs, int* __restrict__ adj, int N) {
    const int b  = blockIdx.x;
    const int lo = boff[b];
    const int sz = boff[b + 1] - lo;
    const int base = b << 8;
    const int t = threadIdx.x;

    __shared__ int hist[256];
    __shared__ int hcur[256];
    __shared__ unsigned sbuf[CAP];

    hist[t] = 0;
    __syncthreads();
    for (int i = t; i < sz; i += 256)
        atomicAdd(&hist[ebuf[lo + i] >> 24], 1);
    __syncthreads();
    int v = hist[t];
    hcur[t] = v;
    __syncthreads();
    for (int o = 1; o < 256; o <<= 1) {
        const int a = (t >= o) ? hcur[t - o] : 0;
        __syncthreads();
        hcur[t] += a;
        __syncthreads();
    }
    const int ex = hcur[t] - v;
    __syncthreads();
    hcur[t] = ex;
    if (base + t < N) offs[base + t] = lo + ex;
    __syncthreads();

    if (sz <= CAP) {
        for (int i = t; i < sz; i += 256) {
            const unsigned w = ebuf[lo + i];
            const int p = atomicAdd(&hcur[w >> 24], 1);
            sbuf[p] = w & 0x00FFFFFFu;
        }
        __syncthreads();
        for (int i = t; i < sz; i += 256) adj[lo + i] = (int)sbuf[i];   // coalesced
    } else {                          // skew fallback (correct, uncoalesced)
        for (int i = t; i < sz; i += 256) {
            const unsigned w = ebuf[lo + i];
            const int p = atomicAdd(&hcur[w >> 24], 1);
            adj[lo + p] = (int)(w & 0x00FFFFFFu);
        }
    }
}

// ---------------- fp32 -> bf16 (RNE) cast, 8 elems/thread ----------------
__global__ __launch_bounds__(256) void cast_bf16(
    const float* __restrict__ in, unsigned short* __restrict__ outb, long long n8) {
    const long long t = (long long)blockIdx.x * 256 + threadIdx.x;
    if (t >= n8) return;
    const float4 v0 = *reinterpret_cast<const float4*>(in + t * 8);
    const float4 v1 = *reinterpret_cast<const float4*>(in + t * 8 + 4);
    uint4 o;
    o.x = rne_bf16(v0.x) | (rne_bf16(v0.y) << 16);
    o.y = rne_bf16(v0.z) | (rne_bf16(v0.w) << 16);
    o.z = rne_bf16(v1.x) | (rne_bf16(v1.y) << 16);
    o.w = rne_bf16(v1.z) | (rne_bf16(v1.w) << 16);
    *reinterpret_cast<uint4*>(outb + t * 8) = o;
}

// ---------------- gather-mean from bf16 rows (8 threads/node) --------------
__global__ __launch_bounds__(256) void aggregate_bf16(
    const unsigned short* __restrict__ xb, float* __restrict__ agg,
    const int* __restrict__ offs, const int* __restrict__ adj, int n) {
    const int t  = blockIdx.x * 256 + threadIdx.x;
    const int nd = t >> 3;
    const int c8 = (t & 7) * 8;
    if (nd >= n) return;

    const int s = offs[nd];
    const int e = offs[nd + 1];

    float a0[8], a1[8], a2[8], a3[8];
#pragma unroll
    for (int p = 0; p < 8; ++p) { a0[p] = 0.f; a1[p] = 0.f; a2[p] = 0.f; a3[p] = 0.f; }

#define ACC8(A, U)                                                             \
    do {                                                                       \
        A[0] += __uint_as_float((U).x << 16);                                  \
        A[1] += __uint_as_float((U).x & 0xFFFF0000u);                          \
        A[2] += __uint_as_float((U).y << 16);                                  \
        A[3] += __uint_as_float((U).y & 0xFFFF0000u);                          \
        A[4] += __uint_as_float((U).z << 16);                                  \
        A[5] += __uint_as_float((U).z & 0xFFFF0000u);                          \
        A[6] += __uint_as_float((U).w << 16);                                  \
        A[7] += __uint_as_float((U).w & 0xFFFF0000u);                          \
    } while (0)

    int j = s;
    for (; j + 4 <= e; j += 4) {
        const int i0 = adj[j], i1 = adj[j + 1], i2 = adj[j + 2], i3 = adj[j + 3];
        const uint4 u0 = *reinterpret_cast<const uint4*>(xb + (size_t)i0 * DD + c8);
        const uint4 u1 = *reinterpret_cast<const uint4*>(xb + (size_t)i1 * DD + c8);
        const uint4 u2 = *reinterpret_cast<const uint4*>(xb + (size_t)i2 * DD + c8);
        const uint4 u3 = *reinterpret_cast<const uint4*>(xb + (size_t)i3 * DD + c8);
        ACC8(a0, u0); ACC8(a1, u1); ACC8(a2, u2); ACC8(a3, u3);
    }
    for (; j < e; ++j) {
        const uint4 u = *reinterpret_cast<const uint4*>(xb + (size_t)adj[j] * DD + c8);
        ACC8(a0, u);
    }
#undef ACC8

    const int deg = e - s;
    const float inv = (deg > 0) ? (1.0f / (float)deg) : 1.0f;
    float4 r0, r1;
    r0.x = (a0[0] + a1[0] + a2[0] + a3[0]) * inv;
    r0.y = (a0[1] + a1[1] + a2[1] + a3[1]) * inv;
    r0.z = (a0[2] + a1[2] + a2[2] + a3[2]) * inv;
    r0.w = (a0[3] + a1[3] + a2[3] + a3[3]) * inv;
    r1.x = (a0[4] + a1[4] + a2[4] + a3[4]) * inv;
    r1.y = (a0[5] + a1[5] + a2[5] + a3[5]) * inv;
    r1.z = (a0[6] + a1[6] + a2[6] + a3[6]) * inv;
    r1.w = (a0[7] + a1[7] + a2[7] + a3[7]) * inv;
    *reinterpret_cast<float4*>(agg + (size_t)nd * DD + c8)     = r0;
    *reinterpret_cast<float4*>(agg + (size_t)nd * DD + c8 + 4) = r1;
}

// ---------------- W pre-pack into MFMA B-fragment layout, bf16 hi/lo --------
__global__ void pack_B(const float* __restrict__ Wl, const float* __restrict__ Wr,
                       unsigned* __restrict__ Bp, int L) {
    int t = blockIdx.x * 256 + threadIdx.x;
    int wv = t >> 6, lane = t & 63;
    if (wv >= L * 16) return;
    int layer = wv >> 4;
    int fid = wv & 15;
    int ks = fid >> 2, nt = fid & 3;
    int j = nt * 16 + (lane & 15);
    int kb = ks * 32 + (lane >> 4) * 8;
    const float* wl = Wl + (size_t)layer * DD * DD;
    const float* wr = Wr + (size_t)layer * DD * DD;
    unsigned hi[8], lo[8];
#pragma unroll
    for (int s = 0; s < 8; ++s) {
        int k = kb + s;
        float v = (k < DD) ? wl[k * DD + j] : wr[(k - DD) * DD + j];
        unsigned u = __float_as_uint(v);
        unsigned h = u & 0xFFFF0000u;
        hi[s] = h;
        float lf = v - __uint_as_float(h);         // exact residual
        lo[s] = __float_as_uint(lf) & 0xFFFF0000u;
    }
    size_t base_hi = ((size_t)(layer * 2 + 0) * 16 + fid) * 64 + lane;
    size_t base_lo = ((size_t)(layer * 2 + 1) * 16 + fid) * 64 + lane;
#pragma unroll
    for (int p = 0; p < 4; ++p) {
        Bp[base_hi * 4 + p] = (hi[2 * p] >> 16) | hi[2 * p + 1];
        Bp[base_lo * 4 + p] = (lo[2 * p] >> 16) | lo[2 * p + 1];
    }
}

// ---------------- layer GEMM: out_bf16 = bias + agg@Wl + x_bf16@Wr ----------
// agg (fp32): exact hi/lo split, 3 MFMAs per frag. x (bf16): A-frag is the
// loaded uint4 directly, 2 MFMAs (Ah*Bh + Ah*Bl). Output written bf16 only.
__global__ __launch_bounds__(256, 2) void mfma_gemm(
    const float* __restrict__ g, const unsigned short* __restrict__ xb,
    unsigned short* __restrict__ outb, const unsigned* __restrict__ Bp,
    const float* __restrict__ bias, int n) {
    const int lane = threadIdx.x & 63;
    const int wv   = (int)((blockIdx.x * 256 + threadIdx.x) >> 6);
    const int nwv  = (int)((gridDim.x * 256) >> 6);

    short8 Bh[4][4], Bl[4][4];
#pragma unroll
    for (int ks = 0; ks < 4; ++ks)
#pragma unroll
        for (int nt = 0; nt < 4; ++nt) {
            int fid = ks * 4 + nt;
            const uint4 h = *reinterpret_cast<const uint4*>(Bp + ((size_t)fid * 64 + lane) * 4);
            const uint4 l = *reinterpret_cast<const uint4*>(Bp + ((size_t)(16 + fid) * 64 + lane) * 4);
            Bh[ks][nt] = pack4(h.x, h.y, h.z, h.w);
            Bl[ks][nt] = pack4(l.x, l.y, l.z, l.w);
        }

    float bv[4];
#pragma unroll
    for (int nt = 0; nt < 4; ++nt) bv[nt] = bias[nt * 16 + (lane & 15)];

    const int ntiles = (n + 15) >> 4;
    for (int tile = wv; tile < ntiles; tile += nwv) {
        const int row = tile * 16 + (lane & 15);
        const bool ok = row < n;
        const float*          grow = g  + (size_t)row * DD + (lane >> 4) * 8;
        const unsigned short* xrow = xb + (size_t)row * DD + (lane >> 4) * 8;

        f32x4 acc[4];
#pragma unroll
        for (int nt = 0; nt < 4; ++nt) acc[nt] = (f32x4){bv[nt], bv[nt], bv[nt], bv[nt]};

        // ---- agg side (fp32, exact hi/lo split): ks = 0,1 ----
#pragma unroll
        for (int ks = 0; ks < 2; ++ks) {
            const float* base = grow + ks * 32;
            f32x4 v0 = ok ? *reinterpret_cast<const f32x4*>(base)
                          : (f32x4){0.f, 0.f, 0.f, 0.f};
            f32x4 v1 = ok ? *reinterpret_cast<const f32x4*>(base + 4)
                          : (f32x4){0.f, 0.f, 0.f, 0.f};
            float vv[8] = {v0[0], v0[1], v0[2], v0[3], v1[0], v1[1], v1[2], v1[3]};
            unsigned hu[4], lu[4];
#pragma unroll
            for (int p = 0; p < 4; ++p) {
                unsigned ua = __float_as_uint(vv[2 * p]);
                unsigned ub = __float_as_uint(vv[2 * p + 1]);
                unsigned ha = ua & 0xFFFF0000u, hb = ub & 0xFFFF0000u;
                hu[p] = (ha >> 16) | hb;
                float la = vv[2 * p]     - __uint_as_float(ha);
                float lb = vv[2 * p + 1] - __uint_as_float(hb);
                lu[p] = ((__float_as_uint(la) & 0xFFFF0000u) >> 16) |
                        (__float_as_uint(lb) & 0xFFFF0000u);
            }
            const short8 Ah = pack4(hu[0], hu[1], hu[2], hu[3]);
            const short8 Al = pack4(lu[0], lu[1], lu[2], lu[3]);
#pragma unroll
            for (int nt = 0; nt < 4; ++nt) {
                acc[nt] = __builtin_amdgcn_mfma_f32_16x16x32_bf16(Ah, Bh[ks][nt], acc[nt], 0, 0, 0);
                acc[nt] = __builtin_amdgcn_mfma_f32_16x16x32_bf16(Al, Bh[ks][nt], acc[nt], 0, 0, 0);
                acc[nt] = __builtin_amdgcn_mfma_f32_16x16x32_bf16(Ah, Bl[ks][nt], acc[nt], 0, 0, 0);
            }
        }

        // ---- x side (bf16 direct): ks = 2,3 ----
#pragma unroll
        for (int ks = 2; ks < 4; ++ks) {
            const uint4 u = ok ? *reinterpret_cast<const uint4*>(xrow + (ks & 1) * 32)
                               : make_uint4(0, 0, 0, 0);
            const short8 Ah = as_short8(u);
#pragma unroll
            for (int nt = 0; nt < 4; ++nt) {
                acc[nt] = __builtin_amdgcn_mfma_f32_16x16x32_bf16(Ah, Bh[ks][nt], acc[nt], 0, 0, 0);
                acc[nt] = __builtin_amdgcn_mfma_f32_16x16x32_bf16(Ah, Bl[ks][nt], acc[nt], 0, 0, 0);
            }
        }

        // C/D layout (verified): col = lane&15, row = (lane>>4)*4 + reg
        const int r0 = tile * 16 + (lane >> 4) * 4;
#pragma unroll
        for (int r = 0; r < 4; ++r) {
            const int rr = r0 + r;
            if (rr < n) {
#pragma unroll
                for (int nt = 0; nt < 4; ++nt) {
                    const size_t idx = (size_t)rr * DD + nt * 16 + (lane & 15);
                    outb[idx] = (unsigned short)rne_bf16(acc[nt][r]);
                }
            }
        }
    }
}

// ---------------- pooling partials: fp32 agg + bf16 x ----------------
__global__ __launch_bounds__(256) void pool_partial2(
    const float* __restrict__ xa, const unsigned short* __restrict__ xb,
    const int* __restrict__ batch,
    float* __restrict__ sumsA, float* __restrict__ sumsB, int n) {
    const int lane = threadIdx.x & 63;
    const int wv   = (int)((blockIdx.x * blockDim.x + threadIdx.x) >> 6);
    const int nwv  = (int)((gridDim.x * blockDim.x) >> 6);
    const int chunk = (n + nwv - 1) / nwv;
    const int start = wv * chunk;
    if (start >= n) return;
    const int end = min(start + chunk, n);

    int g = batch[start];
    float accA = 0.f, accB = 0.f;
    for (int nd = start; nd < end; ++nd) {
        const int bg = batch[nd];
        if (bg != g) {
            atomicAdd(&sumsA[(size_t)g * DD + lane], accA);
            atomicAdd(&sumsB[(size_t)g * DD + lane], accB);
            accA = 0.f; accB = 0.f;
            g = bg;
        }
        accA += xa[(size_t)nd * DD + lane];
        accB += __uint_as_float((unsigned)xb[(size_t)nd * DD + lane] << 16);
    }
    atomicAdd(&sumsA[(size_t)g * DD + lane], accA);
    atomicAdd(&sumsB[(size_t)g * DD + lane], accB);
}

// ---------------- final: out[g] = mean(agg3)@Wl + mean(x2)@Wr + b ----------
__global__ void final_gemm(const float* __restrict__ sumsA, const float* __restrict__ sumsX,
                           const int* __restrict__ batch,
                           const float* __restrict__ Wl, const float* __restrict__ bl,
                           const float* __restrict__ Wr,
                           float* __restrict__ out, int n) {
    const int g = blockIdx.x;
    const int d = threadIdx.x;  // 64 threads

    int lo = 0, hi = n;
    while (lo < hi) { int m = (lo + hi) >> 1; if (batch[m] < g) lo = m + 1; else hi = m; }
    const int st = lo;
    lo = 0; hi = n;
    while (lo < hi) { int m = (lo + hi) >> 1; if (batch[m] < g + 1) lo = m + 1; else hi = m; }
    const int c = lo - st;

    if (c == 0) {                    // reference: empty graph -> 0 (not bias)
        out[(size_t)g * DD + d] = 0.f;
        return;
    }
    const float inv = 1.0f / (float)c;

    __shared__ float sa[DD], sx[DD];
    sa[d] = sumsA[(size_t)g * DD + d] * inv;
    sx[d] = sumsX[(size_t)g * DD + d] * inv;
    __syncthreads();

    float acc = bl[d];
#pragma unroll 8
    for (int k = 0; k < DD; ++k) acc += sa[k] * Wl[k * DD + d];
#pragma unroll 8
    for (int k = 0; k < DD; ++k) acc += sx[k] * Wr[k * DD + d];
    out[(size_t)g * DD + d] = acc;
}

extern "C" void kernel_launch(void* const* d_in, const int* in_sizes, int n_in,
                              void* d_out, int out_size, void* d_ws, size_t ws_size,
                              hipStream_t stream) {
    const float* x     = (const float*)d_in[0];
    const int*   ei    = (const int*)d_in[1];
    const int*   batch = (const int*)d_in[2];
    const float* Wl    = (const float*)d_in[3];
    const float* bl    = (const float*)d_in[4];
    const float* Wr    = (const float*)d_in[5];

    const int N = in_sizes[0] / DD;
    const int E = in_sizes[1] / 2;
    const int L = in_sizes[3] / (DD * DD);
    const int G = out_size / DD;
    const int NBUCK = (N + 255) >> 8;          // 256-node buckets

    const int* src = ei;        // edge_index[0]
    const int* dst = ei + E;    // edge_index[1]

    char* ws = (char*)d_ws;
    size_t off = 0;
    auto alloc = [&](size_t bytes) -> char* {
        char* p = ws + off;
        off += (bytes + 255) & ~(size_t)255;
        return p;
    };
    int*      offs   = (int*)alloc((size_t)(N + 1) * 4);
    int*      adj    = (int*)alloc((size_t)E * 4);
    int*      cnt    = (int*)alloc((size_t)NBA * NBUCK * 4);
    int*      basep  = (int*)alloc((size_t)NBA * NBUCK * 4);
    int*      boff   = (int*)alloc((size_t)(NBUCK + 1) * 4);
    int*      tot    = (int*)alloc((size_t)NBUCK * 4);
    unsigned* ebuf   = (unsigned*)alloc((size_t)E * 4);
    float*    aggbuf = (float*)alloc((size_t)N * DD * 4);
    unsigned* Bp     = (unsigned*)alloc((size_t)L * 2 * 16 * 64 * 4 * 4);
    float*    sumsA  = (float*)alloc((size_t)G * DD * 4);
    float*    sumsX  = (float*)alloc((size_t)G * DD * 4);
    const size_t bfbytes = (size_t)N * DD * 2;
    unsigned short* bfIn = (unsigned short*)alloc(bfbytes);   // cast(x); reused as bf of layer-1 out
    unsigned short* bf0  = (unsigned short*)alloc(bfbytes);   // layer-0 out

    // ---- CSR build: all-coalesced counting sort, parallel prefix passes ----
    const size_t ldsN = (size_t)NBUCK * 4;
    bucket_count<<<NBA, 256, ldsN, stream>>>(dst, cnt, E, NBUCK);
    bucket_prescan<<<(NBUCK * 64 + 255) / 256, 256, 0, stream>>>(cnt, basep, tot, NBUCK);
    bucket_toff<<<1, 1024, 0, stream>>>(tot, boff, offs, NBUCK, E, N);
    bucket_scatter<<<NBA, 256, ldsN, stream>>>(src, dst, basep, boff, ebuf, E, NBUCK);
    bucket_sort<<<NBUCK, 256, 0, stream>>>(ebuf, boff, offs, adj, N);

    // ---- pack W into MFMA fragment layout (all layers) ----
    pack_B<<<(L * 16 * 64 + 255) / 256, 256, 0, stream>>>(Wl, Wr, Bp, L);

    // ---- cast input to bf16 (the only fp32 activation read of x) ----
    const long long n8 = (long long)N * DD / 8;
    cast_bf16<<<(int)((n8 + 255) / 256), 256, 0, stream>>>(x, bfIn, n8);

    // ---- layers 0..L-2: aggregate + MFMA gemm (bf16 ping-pong) ----
    const unsigned short* curb = bfIn;
    unsigned short* bfs[2] = {bf0, bfIn};   // layer 0 -> bf0, layer 1 -> bfIn (dead)
    const int aggB_blocks = (N * 8 + 255) / 256;
    for (int l = 0; l < L - 1; ++l) {
        aggregate_bf16<<<aggB_blocks, 256, 0, stream>>>(curb, aggbuf, offs, adj, N);
        mfma_gemm<<<1024, 256, 0, stream>>>(aggbuf, curb, bfs[l & 1],
                                            Bp + (size_t)l * 2 * 16 * 64 * 4,
                                            bl + (size_t)l * DD, N);
        curb = bfs[l & 1];
    }

    // ---- last layer: pooling is linear -> pool(agg), pool(x), tiny GEMM ----
    aggregate_bf16<<<aggB_blocks, 256, 0, stream>>>(curb, aggbuf, offs, adj, N);
    hipMemsetAsync(sumsA, 0, (size_t)G * DD * 4, stream);
    hipMemsetAsync(sumsX, 0, (size_t)G * DD * 4, stream);
    pool_partial2<<<2048, 256, 0, stream>>>(aggbuf, curb, batch, sumsA, sumsX, N);
    final_gemm<<<G, DD, 0, stream>>>(sumsA, sumsX, batch,
                                     Wl + (size_t)(L - 1) * DD * DD,
                                     bl + (size_t)(L - 1) * DD,
                                     Wr + (size_t)(L - 1) * DD * DD,
                                     (float*)d_out, N);
}

// Round 13
// 178.080 us; speedup vs baseline: 2.6679x; 1.0395x over previous
//
#include <hip/hip_runtime.h>

// GraphSAGE (mean) x3 + per-graph mean pool, MI355X.
// R13: (a) agg buffer -> bf16: halves agg write/read/pool streams AND lets the
// gemm use the bf16-direct A-frag path on BOTH operands (no hi/lo VALU split,
// 32 MFMAs/tile); W keeps its exact hi/lo split for accuracy. (b) gather loop
// 8-deep unrolled (8 outstanding 16B loads/thread) for the latency-bound L3
// gather. (c) single memset for the adjacent sums buffers.

#define DD 64
#define NBA 128    // blocks in count/scatter passes (= 2 x wave width)
#define CAP 4096   // per-bucket LDS sort capacity (avg bucket ~2560 edges)

typedef __attribute__((ext_vector_type(8))) short short8;   // 8 bf16 (4 VGPRs)
typedef __attribute__((ext_vector_type(4))) float f32x4;    // MFMA accumulator

__device__ inline short8 pack4(unsigned a, unsigned b, unsigned c, unsigned d) {
    union { uint4 u; short8 s; } un;
    un.u = make_uint4(a, b, c, d);
    return un.s;
}

__device__ inline short8 as_short8(uint4 u) {
    union { uint4 u4; short8 s; } un;
    un.u4 = u;
    return un.s;
}

__device__ inline unsigned rne_bf16(float v) {   // round-to-nearest-even, high16
    unsigned u = __float_as_uint(v);
    return (u + 0x7FFFu + ((u >> 16) & 1u)) >> 16;
}

// ---------------- CSR 1: per-block bucket histogram ----------------
__global__ __launch_bounds__(256) void bucket_count(
    const int* __restrict__ dst, int* __restrict__ cnt, int E, int NBUCK) {
    extern __shared__ int hist[];   // NBUCK ints
    const int b = blockIdx.x;
    const int per = (E + NBA - 1) / NBA;
    const int lo = b * per, hi = min(lo + per, E);
    for (int k = threadIdx.x; k < NBUCK; k += 256) hist[k] = 0;
    __syncthreads();
    for (int e = lo + threadIdx.x; e < hi; e += 256)
        atomicAdd(&hist[dst[e] >> 8], 1);
    __syncthreads();
    for (int k = threadIdx.x; k < NBUCK; k += 256)
        cnt[b * NBUCK + k] = hist[k];
}

// ---------------- CSR 2a: per-bucket wave scan over 128 block counts --------
__global__ __launch_bounds__(256) void bucket_prescan(
    const int* __restrict__ cnt, int* __restrict__ base,
    int* __restrict__ tot, int NBUCK) {
    const int lane = threadIdx.x & 63;
    const int k = (int)((blockIdx.x * 256 + threadIdx.x) >> 6);
    if (k >= NBUCK) return;
    int v0 = cnt[(size_t)lane * NBUCK + k];
    int v1 = cnt[(size_t)(lane + 64) * NBUCK + k];
    int s0 = v0, s1 = v1;
#pragma unroll
    for (int o = 1; o < 64; o <<= 1) {
        const int u0 = __shfl_up(s0, o, 64);
        const int u1 = __shfl_up(s1, o, 64);
        if (lane >= o) { s0 += u0; s1 += u1; }
    }
    const int total0 = __shfl(s0, 63, 64);
    base[(size_t)lane * NBUCK + k] = s0 - v0;                 // exclusive
    base[(size_t)(lane + 64) * NBUCK + k] = total0 + s1 - v1;
    if (lane == 63) tot[k] = total0 + s1;
}

// ---------------- CSR 2b: exclusive scan over NBUCK bucket totals -----------
__global__ __launch_bounds__(1024) void bucket_toff(
    const int* __restrict__ tot, int* __restrict__ boff,
    int* __restrict__ offs, int NBUCK, int E, int N) {
    __shared__ int s[1024];
    __shared__ int carry_s;
    const int t = threadIdx.x;
    if (t == 0) carry_s = 0;
    __syncthreads();
    for (int cs = 0; cs < NBUCK; cs += 1024) {
        const int i = cs + t;
        const int v = (i < NBUCK) ? tot[i] : 0;
        s[t] = v;
        __syncthreads();
        for (int o = 1; o < 1024; o <<= 1) {
            const int a = (t >= o) ? s[t - o] : 0;
            __syncthreads();
            s[t] += a;
            __syncthreads();
        }
        const int carry = carry_s;
        if (i < NBUCK) boff[i] = carry + s[t] - v;
        __syncthreads();
        if (t == 1023) carry_s = carry + s[1023];
        __syncthreads();
    }
    if (t == 0) { boff[NBUCK] = E; offs[N] = E; }
}

// ---------------- CSR 3: packed scatter into block-private runs -------------
__global__ __launch_bounds__(256) void bucket_scatter(
    const int* __restrict__ src, const int* __restrict__ dst,
    const int* __restrict__ base, const int* __restrict__ boff,
    unsigned* __restrict__ ebuf, int E, int NBUCK) {
    extern __shared__ int pos[];   // NBUCK ints
    const int b = blockIdx.x;
    const int per = (E + NBA - 1) / NBA;
    const int lo = b * per, hi = min(lo + per, E);
    for (int k = threadIdx.x; k < NBUCK; k += 256)
        pos[k] = base[b * NBUCK + k] + boff[k];
    __syncthreads();
    for (int e = lo + threadIdx.x; e < hi; e += 256) {
        const int d = dst[e];
        const int s = src[e];
        const int p = atomicAdd(&pos[d >> 8], 1);          // LDS only
        ebuf[p] = ((unsigned)(d & 255) << 24) | (unsigned)s;
    }
}

// ---------------- CSR 4: per-bucket LDS counting sort -----------------------
__global__ __launch_bounds__(256) void bucket_sort(
    const unsigned* __restrict__ ebuf, const int* __restrict__ boff,
    int* __restrict__ offs, int* __restrict__ adj, int N) {
    const int b  = blockIdx.x;
    const int lo = boff[b];
    const int sz = boff[b + 1] - lo;
    const int base = b << 8;
    const int t = threadIdx.x;

    __shared__ int hist[256];
    __shared__ int hcur[256];
    __shared__ unsigned sbuf[CAP];

    hist[t] = 0;
    __syncthreads();
    for (int i = t; i < sz; i += 256)
        atomicAdd(&hist[ebuf[lo + i] >> 24], 1);
    __syncthreads();
    int v = hist[t];
    hcur[t] = v;
    __syncthreads();
    for (int o = 1; o < 256; o <<= 1) {
        const int a = (t >= o) ? hcur[t - o] : 0;
        __syncthreads();
        hcur[t] += a;
        __syncthreads();
    }
    const int ex = hcur[t] - v;
    __syncthreads();
    hcur[t] = ex;
    if (base + t < N) offs[base + t] = lo + ex;
    __syncthreads();

    if (sz <= CAP) {
        for (int i = t; i < sz; i += 256) {
            const unsigned w = ebuf[lo + i];
            const int p = atomicAdd(&hcur[w >> 24], 1);
            sbuf[p] = w & 0x00FFFFFFu;
        }
        __syncthreads();
        for (int i = t; i < sz; i += 256) adj[lo + i] = (int)sbuf[i];   // coalesced
    } else {                          // skew fallback (correct, uncoalesced)
        for (int i = t; i < sz; i += 256) {
            const unsigned w = ebuf[lo + i];
            const int p = atomicAdd(&hcur[w >> 24], 1);
            adj[lo + p] = (int)(w & 0x00FFFFFFu);
        }
    }
}

// ---------------- fp32 -> bf16 (RNE) cast, 8 elems/thread ----------------
__global__ __launch_bounds__(256) void cast_bf16(
    const float* __restrict__ in, unsigned short* __restrict__ outb, long long n8) {
    const long long t = (long long)blockIdx.x * 256 + threadIdx.x;
    if (t >= n8) return;
    const float4 v0 = *reinterpret_cast<const float4*>(in + t * 8);
    const float4 v1 = *reinterpret_cast<const float4*>(in + t * 8 + 4);
    uint4 o;
    o.x = rne_bf16(v0.x) | (rne_bf16(v0.y) << 16);
    o.y = rne_bf16(v0.z) | (rne_bf16(v0.w) << 16);
    o.z = rne_bf16(v1.x) | (rne_bf16(v1.y) << 16);
    o.w = rne_bf16(v1.z) | (rne_bf16(v1.w) << 16);
    *reinterpret_cast<uint4*>(outb + t * 8) = o;
}

// ---------------- gather-mean bf16 -> bf16 (8 threads/node, 8-deep) --------
__global__ __launch_bounds__(256) void aggregate_bf16(
    const unsigned short* __restrict__ xb, unsigned short* __restrict__ aggb,
    const int* __restrict__ offs, const int* __restrict__ adj, int n) {
    const int t  = blockIdx.x * 256 + threadIdx.x;
    const int nd = t >> 3;
    const int c8 = (t & 7) * 8;
    if (nd >= n) return;

    const int s = offs[nd];
    const int e = offs[nd + 1];

    float a0[8], a1[8], a2[8], a3[8];
#pragma unroll
    for (int p = 0; p < 8; ++p) { a0[p] = 0.f; a1[p] = 0.f; a2[p] = 0.f; a3[p] = 0.f; }

#define ACC8(A, U)                                                             \
    do {                                                                       \
        A[0] += __uint_as_float((U).x << 16);                                  \
        A[1] += __uint_as_float((U).x & 0xFFFF0000u);                          \
        A[2] += __uint_as_float((U).y << 16);                                  \
        A[3] += __uint_as_float((U).y & 0xFFFF0000u);                          \
        A[4] += __uint_as_float((U).z << 16);                                  \
        A[5] += __uint_as_float((U).z & 0xFFFF0000u);                          \
        A[6] += __uint_as_float((U).w << 16);                                  \
        A[7] += __uint_as_float((U).w & 0xFFFF0000u);                          \
    } while (0)

    int j = s;
    for (; j + 8 <= e; j += 8) {        // 8 outstanding row loads
        const int i0 = adj[j],     i1 = adj[j + 1], i2 = adj[j + 2], i3 = adj[j + 3];
        const int i4 = adj[j + 4], i5 = adj[j + 5], i6 = adj[j + 6], i7 = adj[j + 7];
        const uint4 u0 = *reinterpret_cast<const uint4*>(xb + (size_t)i0 * DD + c8);
        const uint4 u1 = *reinterpret_cast<const uint4*>(xb + (size_t)i1 * DD + c8);
        const uint4 u2 = *reinterpret_cast<const uint4*>(xb + (size_t)i2 * DD + c8);
        const uint4 u3 = *reinterpret_cast<const uint4*>(xb + (size_t)i3 * DD + c8);
        const uint4 u4 = *reinterpret_cast<const uint4*>(xb + (size_t)i4 * DD + c8);
        const uint4 u5 = *reinterpret_cast<const uint4*>(xb + (size_t)i5 * DD + c8);
        const uint4 u6 = *reinterpret_cast<const uint4*>(xb + (size_t)i6 * DD + c8);
        const uint4 u7 = *reinterpret_cast<const uint4*>(xb + (size_t)i7 * DD + c8);
        ACC8(a0, u0); ACC8(a1, u1); ACC8(a2, u2); ACC8(a3, u3);
        ACC8(a0, u4); ACC8(a1, u5); ACC8(a2, u6); ACC8(a3, u7);
    }
    for (; j + 4 <= e; j += 4) {
        const int i0 = adj[j], i1 = adj[j + 1], i2 = adj[j + 2], i3 = adj[j + 3];
        const uint4 u0 = *reinterpret_cast<const uint4*>(xb + (size_t)i0 * DD + c8);
        const uint4 u1 = *reinterpret_cast<const uint4*>(xb + (size_t)i1 * DD + c8);
        const uint4 u2 = *reinterpret_cast<const uint4*>(xb + (size_t)i2 * DD + c8);
        const uint4 u3 = *reinterpret_cast<const uint4*>(xb + (size_t)i3 * DD + c8);
        ACC8(a0, u0); ACC8(a1, u1); ACC8(a2, u2); ACC8(a3, u3);
    }
    for (; j < e; ++j) {
        const uint4 u = *reinterpret_cast<const uint4*>(xb + (size_t)adj[j] * DD + c8);
        ACC8(a0, u);
    }
#undef ACC8

    const int deg = e - s;
    const float inv = (deg > 0) ? (1.0f / (float)deg) : 1.0f;
    float r[8];
#pragma unroll
    for (int p = 0; p < 8; ++p) r[p] = (a0[p] + a1[p] + a2[p] + a3[p]) * inv;
    uint4 o;
    o.x = rne_bf16(r[0]) | (rne_bf16(r[1]) << 16);
    o.y = rne_bf16(r[2]) | (rne_bf16(r[3]) << 16);
    o.z = rne_bf16(r[4]) | (rne_bf16(r[5]) << 16);
    o.w = rne_bf16(r[6]) | (rne_bf16(r[7]) << 16);
    *reinterpret_cast<uint4*>(aggb + (size_t)nd * DD + c8) = o;
}

// ---------------- W pre-pack into MFMA B-fragment layout, bf16 hi/lo --------
__global__ void pack_B(const float* __restrict__ Wl, const float* __restrict__ Wr,
                       unsigned* __restrict__ Bp, int L) {
    int t = blockIdx.x * 256 + threadIdx.x;
    int wv = t >> 6, lane = t & 63;
    if (wv >= L * 16) return;
    int layer = wv >> 4;
    int fid = wv & 15;
    int ks = fid >> 2, nt = fid & 3;
    int j = nt * 16 + (lane & 15);
    int kb = ks * 32 + (lane >> 4) * 8;
    const float* wl = Wl + (size_t)layer * DD * DD;
    const float* wr = Wr + (size_t)layer * DD * DD;
    unsigned hi[8], lo[8];
#pragma unroll
    for (int s = 0; s < 8; ++s) {
        int k = kb + s;
        float v = (k < DD) ? wl[k * DD + j] : wr[(k - DD) * DD + j];
        unsigned u = __float_as_uint(v);
        unsigned h = u & 0xFFFF0000u;
        hi[s] = h;
        float lf = v - __uint_as_float(h);         // exact residual
        lo[s] = __float_as_uint(lf) & 0xFFFF0000u;
    }
    size_t base_hi = ((size_t)(layer * 2 + 0) * 16 + fid) * 64 + lane;
    size_t base_lo = ((size_t)(layer * 2 + 1) * 16 + fid) * 64 + lane;
#pragma unroll
    for (int p = 0; p < 4; ++p) {
        Bp[base_hi * 4 + p] = (hi[2 * p] >> 16) | hi[2 * p + 1];
        Bp[base_lo * 4 + p] = (lo[2 * p] >> 16) | lo[2 * p + 1];
    }
}

// ---------------- layer GEMM: outb = bias + aggb@Wl + xb@Wr (all bf16 A) ----
// A-frags are the loaded uint4 directly; W keeps hi/lo split (2 MFMAs/frag).
__global__ __launch_bounds__(256, 2) void mfma_gemm(
    const unsigned short* __restrict__ gb, const unsigned short* __restrict__ xb,
    unsigned short* __restrict__ outb, const unsigned* __restrict__ Bp,
    const float* __restrict__ bias, int n) {
    const int lane = threadIdx.x & 63;
    const int wv   = (int)((blockIdx.x * 256 + threadIdx.x) >> 6);
    const int nwv  = (int)((gridDim.x * 256) >> 6);

    short8 Bh[4][4], Bl[4][4];
#pragma unroll
    for (int ks = 0; ks < 4; ++ks)
#pragma unroll
        for (int nt = 0; nt < 4; ++nt) {
            int fid = ks * 4 + nt;
            const uint4 h = *reinterpret_cast<const uint4*>(Bp + ((size_t)fid * 64 + lane) * 4);
            const uint4 l = *reinterpret_cast<const uint4*>(Bp + ((size_t)(16 + fid) * 64 + lane) * 4);
            Bh[ks][nt] = pack4(h.x, h.y, h.z, h.w);
            Bl[ks][nt] = pack4(l.x, l.y, l.z, l.w);
        }

    float bv[4];
#pragma unroll
    for (int nt = 0; nt < 4; ++nt) bv[nt] = bias[nt * 16 + (lane & 15)];

    const int ntiles = (n + 15) >> 4;
    for (int tile = wv; tile < ntiles; tile += nwv) {
        const int row = tile * 16 + (lane & 15);
        const bool ok = row < n;
        const unsigned short* grow = gb + (size_t)row * DD + (lane >> 4) * 8;
        const unsigned short* xrow = xb + (size_t)row * DD + (lane >> 4) * 8;

        f32x4 acc[4];
#pragma unroll
        for (int nt = 0; nt < 4; ++nt) acc[nt] = (f32x4){bv[nt], bv[nt], bv[nt], bv[nt]};

#pragma unroll
        for (int ks = 0; ks < 4; ++ks) {
            const unsigned short* base = ((ks < 2) ? grow : xrow) + (ks & 1) * 32;
            const uint4 u = ok ? *reinterpret_cast<const uint4*>(base)
                               : make_uint4(0, 0, 0, 0);
            const short8 Ah = as_short8(u);
#pragma unroll
            for (int nt = 0; nt < 4; ++nt) {
                acc[nt] = __builtin_amdgcn_mfma_f32_16x16x32_bf16(Ah, Bh[ks][nt], acc[nt], 0, 0, 0);
                acc[nt] = __builtin_amdgcn_mfma_f32_16x16x32_bf16(Ah, Bl[ks][nt], acc[nt], 0, 0, 0);
            }
        }

        // C/D layout (verified): col = lane&15, row = (lane>>4)*4 + reg
        const int r0 = tile * 16 + (lane >> 4) * 4;
#pragma unroll
        for (int r = 0; r < 4; ++r) {
            const int rr = r0 + r;
            if (rr < n) {
#pragma unroll
                for (int nt = 0; nt < 4; ++nt) {
                    const size_t idx = (size_t)rr * DD + nt * 16 + (lane & 15);
                    outb[idx] = (unsigned short)rne_bf16(acc[nt][r]);
                }
            }
        }
    }
}

// ---------------- pooling partials: both arrays bf16 ----------------
__global__ __launch_bounds__(256) void pool_partial2(
    const unsigned short* __restrict__ xa, const unsigned short* __restrict__ xb,
    const int* __restrict__ batch,
    float* __restrict__ sumsA, float* __restrict__ sumsB, int n) {
    const int lane = threadIdx.x & 63;
    const int wv   = (int)((blockIdx.x * blockDim.x + threadIdx.x) >> 6);
    const int nwv  = (int)((gridDim.x * blockDim.x) >> 6);
    const int chunk = (n + nwv - 1) / nwv;
    const int start = wv * chunk;
    if (start >= n) return;
    const int end = min(start + chunk, n);

    int g = batch[start];
    float accA = 0.f, accB = 0.f;
    for (int nd = start; nd < end; ++nd) {
        const int bg = batch[nd];
        if (bg != g) {
            atomicAdd(&sumsA[(size_t)g * DD + lane], accA);
            atomicAdd(&sumsB[(size_t)g * DD + lane], accB);
            accA = 0.f; accB = 0.f;
            g = bg;
        }
        accA += __uint_as_float((unsigned)xa[(size_t)nd * DD + lane] << 16);
        accB += __uint_as_float((unsigned)xb[(size_t)nd * DD + lane] << 16);
    }
    atomicAdd(&sumsA[(size_t)g * DD + lane], accA);
    atomicAdd(&sumsB[(size_t)g * DD + lane], accB);
}

// ---------------- final: out[g] = mean(agg3)@Wl + mean(x2)@Wr + b ----------
__global__ void final_gemm(const float* __restrict__ sumsA, const float* __restrict__ sumsX,
                           const int* __restrict__ batch,
                           const float* __restrict__ Wl, const float* __restrict__ bl,
                           const float* __restrict__ Wr,
                           float* __restrict__ out, int n) {
    const int g = blockIdx.x;
    const int d = threadIdx.x;  // 64 threads

    int lo = 0, hi = n;
    while (lo < hi) { int m = (lo + hi) >> 1; if (batch[m] < g) lo = m + 1; else hi = m; }
    const int st = lo;
    lo = 0; hi = n;
    while (lo < hi) { int m = (lo + hi) >> 1; if (batch[m] < g + 1) lo = m + 1; else hi = m; }
    const int c = lo - st;

    if (c == 0) {                    // reference: empty graph -> 0 (not bias)
        out[(size_t)g * DD + d] = 0.f;
        return;
    }
    const float inv = 1.0f / (float)c;

    __shared__ float sa[DD], sx[DD];
    sa[d] = sumsA[(size_t)g * DD + d] * inv;
    sx[d] = sumsX[(size_t)g * DD + d] * inv;
    __syncthreads();

    float acc = bl[d];
#pragma unroll 8
    for (int k = 0; k < DD; ++k) acc += sa[k] * Wl[k * DD + d];
#pragma unroll 8
    for (int k = 0; k < DD; ++k) acc += sx[k] * Wr[k * DD + d];
    out[(size_t)g * DD + d] = acc;
}

extern "C" void kernel_launch(void* const* d_in, const int* in_sizes, int n_in,
                              void* d_out, int out_size, void* d_ws, size_t ws_size,
                              hipStream_t stream) {
    const float* x     = (const float*)d_in[0];
    const int*   ei    = (const int*)d_in[1];
    const int*   batch = (const int*)d_in[2];
    const float* Wl    = (const float*)d_in[3];
    const float* bl    = (const float*)d_in[4];
    const float* Wr    = (const float*)d_in[5];

    const int N = in_sizes[0] / DD;
    const int E = in_sizes[1] / 2;
    const int L = in_sizes[3] / (DD * DD);
    const int G = out_size / DD;
    const int NBUCK = (N + 255) >> 8;          // 256-node buckets

    const int* src = ei;        // edge_index[0]
    const int* dst = ei + E;    // edge_index[1]

    char* ws = (char*)d_ws;
    size_t off = 0;
    auto alloc = [&](size_t bytes) -> char* {
        char* p = ws + off;
        off += (bytes + 255) & ~(size_t)255;
        return p;
    };
    int*      offs   = (int*)alloc((size_t)(N + 1) * 4);
    int*      adj    = (int*)alloc((size_t)E * 4);
    int*      cnt    = (int*)alloc((size_t)NBA * NBUCK * 4);
    int*      basep  = (int*)alloc((size_t)NBA * NBUCK * 4);
    int*      boff   = (int*)alloc((size_t)(NBUCK + 1) * 4);
    int*      tot    = (int*)alloc((size_t)NBUCK * 4);
    unsigned* ebuf   = (unsigned*)alloc((size_t)E * 4);
    const size_t bfbytes = (size_t)N * DD * 2;
    unsigned short* aggb = (unsigned short*)alloc(bfbytes);   // bf16 agg
    unsigned* Bp     = (unsigned*)alloc((size_t)L * 2 * 16 * 64 * 4 * 4);
    float*    sumsA  = (float*)alloc((size_t)G * DD * 4);    // adjacent with sumsX
    float*    sumsX  = (float*)alloc((size_t)G * DD * 4);
    unsigned short* bfIn = (unsigned short*)alloc(bfbytes);   // cast(x); reused layer-1 out
    unsigned short* bf0  = (unsigned short*)alloc(bfbytes);   // layer-0 out

    // ---- CSR build: all-coalesced counting sort, parallel prefix passes ----
    const size_t ldsN = (size_t)NBUCK * 4;
    bucket_count<<<NBA, 256, ldsN, stream>>>(dst, cnt, E, NBUCK);
    bucket_prescan<<<(NBUCK * 64 + 255) / 256, 256, 0, stream>>>(cnt, basep, tot, NBUCK);
    bucket_toff<<<1, 1024, 0, stream>>>(tot, boff, offs, NBUCK, E, N);
    bucket_scatter<<<NBA, 256, ldsN, stream>>>(src, dst, basep, boff, ebuf, E, NBUCK);
    bucket_sort<<<NBUCK, 256, 0, stream>>>(ebuf, boff, offs, adj, N);

    // ---- pack W into MFMA fragment layout (all layers) ----
    pack_B<<<(L * 16 * 64 + 255) / 256, 256, 0, stream>>>(Wl, Wr, Bp, L);

    // ---- cast input to bf16 (the only fp32 activation read of x) ----
    const long long n8 = (long long)N * DD / 8;
    cast_bf16<<<(int)((n8 + 255) / 256), 256, 0, stream>>>(x, bfIn, n8);

    // ---- layers 0..L-2: aggregate + MFMA gemm (bf16 ping-pong) ----
    const unsigned short* curb = bfIn;
    unsigned short* bfs[2] = {bf0, bfIn};   // layer 0 -> bf0, layer 1 -> bfIn (dead)
    const int aggB_blocks = (N * 8 + 255) / 256;
    for (int l = 0; l < L - 1; ++l) {
        aggregate_bf16<<<aggB_blocks, 256, 0, stream>>>(curb, aggb, offs, adj, N);
        mfma_gemm<<<1024, 256, 0, stream>>>(aggb, curb, bfs[l & 1],
                                            Bp + (size_t)l * 2 * 16 * 64 * 4,
                                            bl + (size_t)l * DD, N);
        curb = bfs[l & 1];
    }

    // ---- last layer: pooling is linear -> pool(agg), pool(x), tiny GEMM ----
    aggregate_bf16<<<aggB_blocks, 256, 0, stream>>>(curb, aggb, offs, adj, N);
    hipMemsetAsync(sumsA, 0, (size_t)G * DD * 4 * 2, stream);   // sumsA+sumsX adjacent
    pool_partial2<<<2048, 256, 0, stream>>>(aggb, curb, batch, sumsA, sumsX, N);
    final_gemm<<<G, DD, 0, stream>>>(sumsA, sumsX, batch,
                                     Wl + (size_t)(L - 1) * DD * DD,
                                     bl + (size_t)(L - 1) * DD,
                                     Wr + (size_t)(L - 1) * DD * DD,
                                     (float*)d_out, N);
}